// Round 11
// baseline (27585.849 us; speedup 1.0000x reference)
//
#include <hip/hip_runtime.h>
#include <cstdio>
#include <cstddef>

enum { ACT_NONE = 0, ACT_LEAKY = 1, ACT_RELU = 2 };

__device__ __forceinline__ float leakyf(float x) { return x > 0.f ? x : 0.01f * x; }

// order-preserving float -> uint encoding for atomicMax
__device__ __forceinline__ unsigned fenc(float f) {
    unsigned u = __float_as_uint(f);
    return (u & 0x80000000u) ? ~u : (u | 0x80000000u);
}
__device__ __forceinline__ float fdec(unsigned u) {
    return (u & 0x80000000u) ? __uint_as_float(u & 0x7FFFFFFFu) : __uint_as_float(~u);
}

// ---------------------------------------------------------------------------
// fp32 GEMM, NC = 128 fixed:  C[r][c] = actOut( A'[r][:] @ B + bias )
//   A' row r = concat( A[idx? idx[r] : r][0:K1], A2[r][0:K-K1] ).
//   B: [K][128] row-major.
// 256 threads, tile 128 rows x 128 cols, micro 8x8, KT=16.
// In-place (C == A) safe: block reads only its own rows, writes in epilogue.
// ---------------------------------------------------------------------------
__global__ __launch_bounds__(256, 2) void gemm_k(
    const float* __restrict__ A, const float* __restrict__ A2,
    const int* __restrict__ idx,
    const float* __restrict__ B, const float* __restrict__ bias,
    float* __restrict__ C, int M, int K, int K1, int actOut)
{
    __shared__ float Xs[16][128];
    __shared__ float Ws[16][128];
    const int t  = threadIdx.x;
    const int tx = t & 15;   // cols tx*8..+7
    const int ty = t >> 4;   // rows ty*8..+7
    const int rowBase = blockIdx.x * 128;

    float acc[8][8];
#pragma unroll
    for (int i = 0; i < 8; i++)
#pragma unroll
        for (int j = 0; j < 8; j++) acc[i][j] = 0.f;

    const int rS = t >> 1;          // 0..127
    const int kS = (t & 1) << 3;    // 0 or 8
    const int K2 = K - K1;

    for (int k0 = 0; k0 < K; k0 += 16) {
        // ---- stage A tile (transposed) ----
        {
            float v[8] = {0.f,0.f,0.f,0.f,0.f,0.f,0.f,0.f};
            const int row = rowBase + rS;
            if (row < M) {
                const int ar = idx ? idx[row] : row;
                const float* __restrict__ a1 = A + (size_t)ar * K1;
                if (((K1 & 3) == 0) && (k0 + kS + 8 <= K1)) {
                    const float4 a = *(const float4*)&a1[k0 + kS];
                    const float4 b = *(const float4*)&a1[k0 + kS + 4];
                    v[0]=a.x; v[1]=a.y; v[2]=a.z; v[3]=a.w;
                    v[4]=b.x; v[5]=b.y; v[6]=b.z; v[7]=b.w;
                } else {
#pragma unroll
                    for (int j = 0; j < 8; j++) {
                        const int k = k0 + kS + j;
                        float x = 0.f;
                        if (k < K1)     x = a1[k];
                        else if (k < K) x = A2[(size_t)row * K2 + (k - K1)];
                        v[j] = x;
                    }
                }
            }
#pragma unroll
            for (int j = 0; j < 8; j++) Xs[kS + j][rS] = v[j];
        }
        // ---- stage B tile ----
        {
            const int cc = (t & 31) << 2;
#pragma unroll
            for (int p = 0; p < 2; p++) {
                const int kk = (t >> 5) + p * 8;
                const int k  = k0 + kk;
                float4 wv = make_float4(0.f, 0.f, 0.f, 0.f);
                if (k < K) wv = *(const float4*)&B[(size_t)k * 128 + cc];
                *(float4*)&Ws[kk][cc] = wv;
            }
        }
        __syncthreads();
#pragma unroll
        for (int k = 0; k < 16; k++) {
            const float4 xa = *(const float4*)&Xs[k][ty << 3];
            const float4 xb = *(const float4*)&Xs[k][(ty << 3) + 4];
            const float4 wa = *(const float4*)&Ws[k][tx << 3];
            const float4 wb = *(const float4*)&Ws[k][(tx << 3) + 4];
            const float xs[8] = {xa.x, xa.y, xa.z, xa.w, xb.x, xb.y, xb.z, xb.w};
            const float ws[8] = {wa.x, wa.y, wa.z, wa.w, wb.x, wb.y, wb.z, wb.w};
#pragma unroll
            for (int i = 0; i < 8; i++)
#pragma unroll
                for (int j = 0; j < 8; j++)
                    acc[i][j] = fmaf(xs[i], ws[j], acc[i][j]);
        }
        __syncthreads();
    }

    const int c0 = tx << 3;
#pragma unroll
    for (int i = 0; i < 8; i++) {
        const int row = rowBase + (ty << 3) + i;
        if (row >= M) continue;
        float o[8];
#pragma unroll
        for (int j = 0; j < 8; j++) {
            float v = acc[i][j] + bias[c0 + j];
            if (actOut == ACT_LEAKY)      v = v > 0.f ? v : 0.01f * v;
            else if (actOut == ACT_RELU)  v = fmaxf(v, 0.f);
            o[j] = v;
        }
        float* __restrict__ cp = C + (size_t)row * 128 + c0;
        *(float4*)cp       = make_float4(o[0], o[1], o[2], o[3]);
        *(float4*)(cp + 4) = make_float4(o[4], o[5], o[6], o[7]);
    }
}

// ---------------------------------------------------------------------------
// Split GRU GEMM (K=128, NC=384, W [384][128] = weight.T layout).
// 256 threads, tile 64 rows; micro 8 rows x (3 gates x 4 dims) = 96 acc.
// Register-staged DOUBLE BUFFER: tile k+1 global loads issue before compute
// of tile k (latency hides under 16x96 FMA); one barrier per k-block.
// As padded to 68 floats/row: staging writes 2-way bank aliases (free) vs
// 4-way at stride 64 (round 9/10: 3.6M conflict cycles/dispatch).
//   GATE=false: gi = elu(A) @ W.T + bias                (A = c)
//   GATE=true : gh = A @ W.T + bias in regs; h = relu(gru(gi, gh, h))
// ---------------------------------------------------------------------------
template <bool GATE>
__global__ __launch_bounds__(256, 2) void gru_gemm_k(
    const float* __restrict__ A, const float* __restrict__ W,
    const float* __restrict__ bias,
    float* __restrict__ gi, float* __restrict__ h, int M)
{
    __shared__ float As[2][16][68];    // [buf][k][row] pad 68 (16B-aligned rows)
    __shared__ float Ws[2][16][388];   // [buf][k][col] pad 388
    const int t  = threadIdx.x;
    const int cg = t & 31;           // gate-dim block cg*4..+3
    const int rg = t >> 5;           // rows rg*8..+7 (0..7)
    const int rowBase = blockIdx.x * 64;

    float acc[3][8][4];
#pragma unroll
    for (int g = 0; g < 3; g++)
#pragma unroll
        for (int i = 0; i < 8; i++)
#pragma unroll
            for (int j = 0; j < 4; j++) acc[g][i][j] = 0.f;

    const int rS = t >> 2;           // 0..63
    const int kS = (t & 3) << 2;     // 0,4,8,12
    const int arow = rowBase + rS;
    const bool arow_ok = (arow < M);

    // W chunks: p=0..5 -> col = rS + 64p, rows kS..kS+3 (q=t+256p: q&3 == t&3)
    float4 wreg[6];
    float4 areg;

    auto load_tile = [&](int k0) {
        const float* __restrict__ wp = W + k0 + kS;
#pragma unroll
        for (int p = 0; p < 6; p++)
            wreg[p] = *(const float4*)&wp[(size_t)(rS + 64 * p) * 128];
        areg = make_float4(0.f, 0.f, 0.f, 0.f);
        if (arow_ok) {
            areg = *(const float4*)&A[(size_t)arow * 128 + k0 + kS];
            if (!GATE) {
                areg.x = areg.x > 0.f ? areg.x : expm1f(areg.x);
                areg.y = areg.y > 0.f ? areg.y : expm1f(areg.y);
                areg.z = areg.z > 0.f ? areg.z : expm1f(areg.z);
                areg.w = areg.w > 0.f ? areg.w : expm1f(areg.w);
            }
        }
    };
    auto store_tile = [&](int b) {
#pragma unroll
        for (int p = 0; p < 6; p++) {
            const int col = rS + 64 * p;
            Ws[b][kS + 0][col] = wreg[p].x;
            Ws[b][kS + 1][col] = wreg[p].y;
            Ws[b][kS + 2][col] = wreg[p].z;
            Ws[b][kS + 3][col] = wreg[p].w;
        }
        As[b][kS + 0][rS] = areg.x;
        As[b][kS + 1][rS] = areg.y;
        As[b][kS + 2][rS] = areg.z;
        As[b][kS + 3][rS] = areg.w;
    };

    load_tile(0);
    store_tile(0);
    __syncthreads();

    for (int kb = 0; kb < 8; kb++) {
        const int cur = kb & 1;
        if (kb < 7) load_tile((kb + 1) * 16);   // issue next-tile loads early
        // ---- compute on buf[cur]: 16 k-steps, 96 FMA each ----
#pragma unroll
        for (int k = 0; k < 16; k++) {
            const float4 a0 = *(const float4*)&As[cur][k][rg << 3];
            const float4 a1 = *(const float4*)&As[cur][k][(rg << 3) + 4];
            const float ar[8] = {a0.x, a0.y, a0.z, a0.w, a1.x, a1.y, a1.z, a1.w};
            const float4 w0 = *(const float4*)&Ws[cur][k][(cg << 2)];
            const float4 w1 = *(const float4*)&Ws[cur][k][128 + (cg << 2)];
            const float4 w2 = *(const float4*)&Ws[cur][k][256 + (cg << 2)];
            const float wv[3][4] = {{w0.x, w0.y, w0.z, w0.w},
                                    {w1.x, w1.y, w1.z, w1.w},
                                    {w2.x, w2.y, w2.z, w2.w}};
#pragma unroll
            for (int g = 0; g < 3; g++)
#pragma unroll
                for (int i = 0; i < 8; i++)
#pragma unroll
                    for (int j = 0; j < 4; j++)
                        acc[g][i][j] = fmaf(ar[i], wv[g][j], acc[g][i][j]);
        }
        if (kb < 7) store_tile(cur ^ 1);        // write next tile to other buf
        __syncthreads();
    }

    const int c0 = cg << 2;
#pragma unroll
    for (int i = 0; i < 8; i++) {
        const int row = rowBase + (rg << 3) + i;
        if (row >= M) continue;
        if (!GATE) {
            float* __restrict__ gp = gi + (size_t)row * 384;
#pragma unroll
            for (int g = 0; g < 3; g++) {
                float4 o;
                o.x = acc[g][i][0] + bias[g * 128 + c0 + 0];
                o.y = acc[g][i][1] + bias[g * 128 + c0 + 1];
                o.z = acc[g][i][2] + bias[g * 128 + c0 + 2];
                o.w = acc[g][i][3] + bias[g * 128 + c0 + 3];
                *(float4*)(gp + g * 128 + c0) = o;
            }
        } else {
            const float* __restrict__ gp = gi + (size_t)row * 384;
            const float4 q0 = *(const float4*)(gp + c0);
            const float4 q1 = *(const float4*)(gp + 128 + c0);
            const float4 q2 = *(const float4*)(gp + 256 + c0);
            const float4 hq = *(const float4*)&h[(size_t)row * 128 + c0];
            const float ir[4] = {q0.x, q0.y, q0.z, q0.w};
            const float iz[4] = {q1.x, q1.y, q1.z, q1.w};
            const float ig[4] = {q2.x, q2.y, q2.z, q2.w};
            const float hv[4] = {hq.x, hq.y, hq.z, hq.w};
            float o[4];
#pragma unroll
            for (int j = 0; j < 4; j++) {
                const float hr = acc[0][i][j] + bias[c0 + j];
                const float hz = acc[1][i][j] + bias[128 + c0 + j];
                const float hg = acc[2][i][j] + bias[256 + c0 + j];
                const float r  = 1.f / (1.f + expf(-(ir[j] + hr)));
                const float z  = 1.f / (1.f + expf(-(iz[j] + hz)));
                const float nn = tanhf(ig[j] + r * hg);
                o[j] = fmaxf((1.f - z) * nn + z * hv[j], 0.f);
            }
            *(float4*)&h[(size_t)row * 128 + c0] = make_float4(o[0], o[1], o[2], o[3]);
        }
    }
}

// ---------------------------------------------------------------------------
// per-node dual dot: pd[i] = h[i]·wa, ps[i] = h[i]·wb   (one wave per node)
// ---------------------------------------------------------------------------
__global__ __launch_bounds__(256) void node_dots_k(
    const float* __restrict__ h, const float* __restrict__ wa,
    const float* __restrict__ wb, float* __restrict__ pd, float* __restrict__ ps, int n)
{
    const int i = blockIdx.x * 4 + (threadIdx.x >> 6);
    const int l = threadIdx.x & 63;
    if (i >= n) return;
    const float2 hv = *(const float2*)&h[(size_t)i * 128 + l * 2];
    float a = hv.x * wa[l * 2] + hv.y * wa[l * 2 + 1];
    float b = 0.f;
    if (wb) b = hv.x * wb[l * 2] + hv.y * wb[l * 2 + 1];
#pragma unroll
    for (int o = 32; o; o >>= 1) {
        a += __shfl_down(a, o, 64);
        b += __shfl_down(b, o, 64);
    }
    if (l == 0) {
        pd[i] = a;
        if (ps) ps[i] = b;
    }
}

// GetContext edge logits from precomputed pe: lg = leaky(pd[dst]+pe[e]+b2); atomicMax m
__global__ __launch_bounds__(256) void edge_lgc_k(
    const float* __restrict__ pd, const float* __restrict__ pe,
    const float* __restrict__ b2, const int* __restrict__ dst,
    float* __restrict__ lg, unsigned* __restrict__ m_u, int E)
{
    const int e = blockIdx.x * blockDim.x + threadIdx.x;
    if (e >= E) return;
    const int d = dst[e];
    const float v = leakyf(pd[d] + pe[e] + b2[0]);
    lg[e] = v;
    atomicMax(&m_u[d], fenc(v));
}

// e = exp(lg - m[dst]); s[dst] += e
__global__ __launch_bounds__(256) void edge_exp_k(
    float* __restrict__ lg, const unsigned* __restrict__ m_u,
    float* __restrict__ s, const int* __restrict__ dst, int E)
{
    const int e = blockIdx.x * blockDim.x + threadIdx.x;
    if (e >= E) return;
    const int d = dst[e];
    const float ex = expf(lg[e] - fdec(m_u[d]));
    lg[e] = ex;
    atomicAdd(&s[d], ex);
}

// c[dst[e]] += (ee[e]/s[dst[e]]) * rows[e]   (64 lanes x 2 cols) -- GetContext only
__global__ __launch_bounds__(256) void scatter_c_k(
    const float* __restrict__ rows,
    const float* __restrict__ ee, const float* __restrict__ s,
    const int* __restrict__ dst, float* __restrict__ c, int E)
{
    const long long gid = (long long)blockIdx.x * blockDim.x + threadIdx.x;
    const int e = (int)(gid >> 6);
    const int l = (int)(gid & 63);
    if (e >= E) return;
    const int d = dst[e];
    const float a = ee[e] / s[d];
    const float2 v = *(const float2*)&rows[(size_t)e * 128 + l * 2];
    atomicAdd(&c[(size_t)d * 128 + l * 2], a * v.x);
    atomicAdd(&c[(size_t)d * 128 + l * 2 + 1], a * v.y);
}

// ---------------------------------------------------------------------------
// CSR build: histogram -> exclusive scan -> fill
// ---------------------------------------------------------------------------
__global__ __launch_bounds__(256) void hist_k(
    const int* __restrict__ dst, unsigned* __restrict__ cnt, int E)
{
    const int e = blockIdx.x * blockDim.x + threadIdx.x;
    if (e < E) atomicAdd(&cnt[dst[e]], 1u);
}

__global__ __launch_bounds__(1024) void scan_k(
    const unsigned* __restrict__ cnt, int* __restrict__ rp, int N)
{
    __shared__ int wsum[16];
    __shared__ int carry;
    const int t = threadIdx.x, lane = t & 63, wid = t >> 6;
    if (t == 0) carry = 0;
    __syncthreads();
    for (int base = 0; base < N; base += 1024) {
        const int i = base + t;
        const int v = (i < N) ? (int)cnt[i] : 0;
        int x = v;
#pragma unroll
        for (int o = 1; o < 64; o <<= 1) {
            const int y = __shfl_up(x, o, 64);
            if (lane >= o) x += y;
        }
        if (lane == 63) wsum[wid] = x;
        __syncthreads();
        if (wid == 0) {
            const int wv = (lane < 16) ? wsum[lane] : 0;
            int wx = wv;
#pragma unroll
            for (int o = 1; o < 16; o <<= 1) {
                const int y = __shfl_up(wx, o, 64);
                if (lane >= o) wx += y;
            }
            if (lane < 16) wsum[lane] = wx - wv;   // exclusive wave offsets
        }
        __syncthreads();
        const int excl = carry + wsum[wid] + x - v;
        if (i < N) rp[i] = excl;
        __syncthreads();
        if (t == 1023) carry = excl + v;
        __syncthreads();
    }
    if (t == 0) rp[N] = carry;
}

__global__ __launch_bounds__(256) void fill_csr_k(
    const int* __restrict__ dst, int* __restrict__ pos,
    int* __restrict__ eidx, int E)
{
    const int e = blockIdx.x * blockDim.x + threadIdx.x;
    if (e < E) {
        const int p = atomicAdd(&pos[dst[e]], 1);
        eidx[p] = e;
    }
}

// ---------------------------------------------------------------------------
// Fused per-node edge softmax + weighted gather (layers):
//   c[d] = sum_e softmax_e( leaky(pd[d]+ps[src[e]]+b) ) * hp[src[e]]
// one wave per node, no atomics, coalesced c write.
// ---------------------------------------------------------------------------
__global__ __launch_bounds__(256) void layer_gather_k(
    const int* __restrict__ rp, const int* __restrict__ eidx,
    const int* __restrict__ src,
    const float* __restrict__ pd, const float* __restrict__ ps,
    const float* __restrict__ bpe,
    const float* __restrict__ hp, float* __restrict__ c, int N)
{
    const int d = blockIdx.x * 4 + (threadIdx.x >> 6);
    const int l = threadIdx.x & 63;
    if (d >= N) return;
    const int beg = rp[d], end = rp[d + 1];
    float acc0 = 0.f, acc1 = 0.f;
    if (beg < end) {
        const float pdd = pd[d];
        const float b   = bpe[0];
        float m = -3.4e38f;
        for (int e = beg + l; e < end; e += 64)
            m = fmaxf(m, leakyf(pdd + ps[src[eidx[e]]] + b));
#pragma unroll
        for (int o = 32; o; o >>= 1) m = fmaxf(m, __shfl_xor(m, o, 64));
        float s = 0.f;
        for (int e = beg + l; e < end; e += 64)
            s += expf(leakyf(pdd + ps[src[eidx[e]]] + b) - m);
#pragma unroll
        for (int o = 32; o; o >>= 1) s += __shfl_xor(s, o, 64);
        const float inv = 1.f / s;
        for (int e = beg; e < end; ++e) {
            const int sr = src[eidx[e]];                 // uniform -> broadcast
            const float a = expf(leakyf(pdd + ps[sr] + b) - m) * inv;
            const float2 v = *(const float2*)&hp[(size_t)sr * 128 + l * 2];
            acc0 = fmaf(a, v.x, acc0);
            acc1 = fmaf(a, v.y, acc1);
        }
    }
    *(float2*)&c[(size_t)d * 128 + l * 2] = make_float2(acc0, acc1);
}

__global__ __launch_bounds__(256) void readout_scatter_k(
    const float* __restrict__ x, const int* __restrict__ gidv,
    float* __restrict__ out, int* __restrict__ counts, int n)
{
    const int i = blockIdx.x * 4 + (threadIdx.x >> 6);
    const int l = threadIdx.x & 63;
    if (i >= n) return;
    const int g = gidv[i];
    const float2 v = *(const float2*)&x[(size_t)i * 128 + l * 2];
    atomicAdd(&out[(size_t)g * 128 + l * 2], v.x);
    atomicAdd(&out[(size_t)g * 128 + l * 2 + 1], v.y);
    if (l == 0) atomicAdd(&counts[g], 1);
}

__global__ __launch_bounds__(256) void readout_div_k(
    float* __restrict__ out, const int* __restrict__ counts, int G)
{
    const int gid = blockIdx.x * blockDim.x + threadIdx.x;
    if (gid >= G * 128) return;
    out[gid] /= fmaxf((float)counts[gid >> 7], 1.f);
}

// ---------------------------------------------------------------------------
extern "C" void kernel_launch(void* const* d_in, const int* in_sizes, int n_in,
                              void* d_out, int out_size, void* d_ws, size_t ws_size,
                              hipStream_t stream)
{
    const float* atom   = (const float*)d_in[0];
    const float* bond   = (const float*)d_in[1];
    const int*   src    = (const int*)d_in[2];
    const int*   dst    = (const int*)d_in[3];
    const int*   ngid   = (const int*)d_in[4];
    const float* W_node = (const float*)d_in[5];
    const float* b_node = (const float*)d_in[6];
    const float* W_e1   = (const float*)d_in[7];
    const float* b_e1   = (const float*)d_in[8];
    const float* W_e2   = (const float*)d_in[9];
    const float* b_e2   = (const float*)d_in[10];
    const float* W_et   = (const float*)d_in[11];
    const float* b_et   = (const float*)d_in[12];
    const float* g0_Wih = (const float*)d_in[13];
    const float* g0_bih = (const float*)d_in[14];
    const float* g0_Whh = (const float*)d_in[15];
    const float* g0_bhh = (const float*)d_in[16];
    const float* Wpe    = (const float*)d_in[17];
    const float* bpe    = (const float*)d_in[18];
    const float* Wpn    = (const float*)d_in[19];
    const float* bpn    = (const float*)d_in[20];
    const float* gWih   = (const float*)d_in[21];
    const float* gbih   = (const float*)d_in[22];
    const float* gWhh   = (const float*)d_in[23];
    const float* gbhh   = (const float*)d_in[24];
    const float* Wr1    = (const float*)d_in[25];
    const float* br1    = (const float*)d_in[26];
    const float* Wr2    = (const float*)d_in[27];
    const float* br2    = (const float*)d_in[28];

    const int N = in_sizes[0] / 74;
    const int E = in_sizes[1] / 12;
    const int G = out_size / 128;
    const int L = in_sizes[18];   // bpe is [L][1]

    char* w = (char*)d_ws;
    auto align256 = [](size_t b) { return (b + 255) & ~(size_t)255; };
    auto alloc = [&](size_t bytes) {
        void* p = (void*)w;
        w += align256(bytes);
        return p;
    };
    // region 1: live across GRU
    float* h    = (float*)alloc((size_t)N * 128 * 4);
    float* c    = (float*)alloc((size_t)N * 128 * 4);
    int*   rp   = (int*)alloc((size_t)(N + 1) * 4);
    int*   posb = (int*)alloc((size_t)N * 4);
    int*   eidx = (int*)alloc((size_t)E * 4);
    int*   cnts = (int*)alloc((size_t)G * 4);
    // union region: gi (N*384) overlays {hp, pd, ps, m_u, sden, pe, lg},
    // all dead during the GRU phase.
    char* ubase = w;
    float* gi = (float*)ubase;
    char* u = ubase;
    auto ualloc = [&](size_t bytes) {
        void* p = (void*)u;
        u += align256(bytes);
        return p;
    };
    float*    hp   = (float*)ualloc((size_t)N * 128 * 4);
    float*    pd   = (float*)ualloc((size_t)N * 4);
    float*    ps   = (float*)ualloc((size_t)N * 4);
    unsigned* m_u  = (unsigned*)ualloc((size_t)N * 4);
    float*    sden = (float*)ualloc((size_t)N * 4);
    float*    pe   = (float*)ualloc((size_t)E * 4);
    float*    lg   = (float*)ualloc((size_t)E * 4);
    const size_t usize = (size_t)(u - ubase) > (size_t)N * 384 * 4
                             ? (size_t)(u - ubase) : (size_t)N * 384 * 4;
    const size_t need = (size_t)(ubase - (char*)d_ws) + align256(usize);
    if (need > ws_size) {
        fprintf(stderr, "kernel_launch: ws too small: need %zu, have %zu\n",
                need, ws_size);
        return;
    }
    float* out = (float*)d_out;

    const dim3 blk(256);
    auto g128 = [](int M) { return dim3((unsigned)((M + 127) / 128)); };
    auto g64  = [](int M) { return dim3((unsigned)((M + 63) / 64)); };
    const dim3 gEdge((unsigned)((E + 255) / 256));
    const dim3 gWave4N((unsigned)((N + 3) / 4));
    const int  Ecap = N;           // hp holds up to N rows

    auto run_gru = [&](const float* Wih, const float* bih,
                       const float* Whh, const float* bhh) {
        gru_gemm_k<false><<<g64(N), blk, 0, stream>>>(c, Wih, bih, gi, nullptr, N);
        gru_gemm_k<true><<<g64(N), blk, 0, stream>>>(h, Whh, bhh, gi, h, N);
    };

    // ---------------- CSR build (graph static across layers) ----------------
    hipMemsetAsync(m_u, 0, (size_t)N * 4, stream);
    hist_k<<<gEdge, blk, 0, stream>>>(dst, m_u, E);
    scan_k<<<dim3(1), dim3(1024), 0, stream>>>(m_u, rp, N);
    hipMemcpyAsync(posb, rp, (size_t)N * 4, hipMemcpyDeviceToDevice, stream);
    fill_csr_k<<<gEdge, blk, 0, stream>>>(dst, posb, eidx, E);

    // ---------------- GetContext ----------------
    gemm_k<<<g128(N), blk, 0, stream>>>(
        atom, nullptr, nullptr, W_node, b_node, h, N, 74, 74, ACT_LEAKY);
    node_dots_k<<<gWave4N, blk, 0, stream>>>(h, W_e2, nullptr, pd, nullptr, N);
    // pass A: pe[e] = he1[e] . W_e2[128:256]  (chunked, he1 in hp, discarded)
    for (int base = 0; base < E; base += Ecap) {
        const int ec = (E - base) < Ecap ? (E - base) : Ecap;
        gemm_k<<<g128(ec), blk, 0, stream>>>(
            atom, bond + (size_t)base * 12, src + base, W_e1, b_e1, hp,
            ec, 86, 74, ACT_LEAKY);
        node_dots_k<<<dim3((unsigned)((ec + 3) / 4)), blk, 0, stream>>>(
            hp, W_e2 + 128, nullptr, pe + base, nullptr, ec);
    }
    hipMemsetAsync(m_u, 0, (size_t)N * 4, stream);
    hipMemsetAsync(sden, 0, (size_t)N * 4, stream);
    edge_lgc_k<<<gEdge, blk, 0, stream>>>(pd, pe, b_e2, dst, lg, m_u, E);
    edge_exp_k<<<gEdge, blk, 0, stream>>>(lg, m_u, sden, dst, E);
    // pass B: recompute he1 chunk, scatter a*he1 into c; then c = c@W_et + b_et
    // (valid since softmax weights sum to 1 per node)
    hipMemsetAsync(c, 0, (size_t)N * 128 * 4, stream);
    for (int base = 0; base < E; base += Ecap) {
        const int ec = (E - base) < Ecap ? (E - base) : Ecap;
        gemm_k<<<g128(ec), blk, 0, stream>>>(
            atom, bond + (size_t)base * 12, src + base, W_e1, b_e1, hp,
            ec, 86, 74, ACT_LEAKY);
        scatter_c_k<<<dim3((unsigned)(((long long)ec * 64 + 255) / 256)), blk, 0, stream>>>(
            hp, lg + base, sden, dst + base, c, ec);
    }
    gemm_k<<<g128(N), blk, 0, stream>>>(
        c, nullptr, nullptr, W_et, b_et, c, N, 128, 128, ACT_NONE);
    run_gru(g0_Wih, g0_bih, g0_Whh, g0_bhh);

    // ---------------- 11 GNN layers ----------------
    for (int l = 0; l < L; ++l) {
        node_dots_k<<<gWave4N, blk, 0, stream>>>(
            h, Wpe + (size_t)l * 256, Wpe + (size_t)l * 256 + 128, pd, ps, N);
        gemm_k<<<g128(N), blk, 0, stream>>>(
            h, nullptr, nullptr, Wpn + (size_t)l * 16384, bpn + (size_t)l * 128,
            hp, N, 128, 128, ACT_NONE);
        layer_gather_k<<<gWave4N, blk, 0, stream>>>(
            rp, eidx, src, pd, ps, bpe + l, hp, c, N);
        run_gru(gWih + (size_t)l * 49152, gbih + (size_t)l * 384,
                gWhh + (size_t)l * 49152, gbhh + (size_t)l * 384);
    }

    // ---------------- readout ----------------
    gemm_k<<<g128(N), blk, 0, stream>>>(
        h, nullptr, nullptr, Wr1, br1, c, N, 128, 128, ACT_RELU);
    gemm_k<<<g128(N), blk, 0, stream>>>(
        c, nullptr, nullptr, Wr2, br2, hp, N, 128, 128, ACT_NONE);
    hipMemsetAsync(out, 0, (size_t)G * 128 * 4, stream);
    hipMemsetAsync(cnts, 0, (size_t)G * 4, stream);
    readout_scatter_k<<<gWave4N, blk, 0, stream>>>(hp, ngid, out, cnts, N);
    readout_div_k<<<dim3((unsigned)((G * 128 + 255) / 256)), blk, 0, stream>>>(out, cnts, G);

    (void)n_in;
}

// Round 12
// 5694.249 us; speedup vs baseline: 4.8445x; 4.8445x over previous
//
#include <hip/hip_runtime.h>
#include <cstdio>
#include <cstddef>

enum { ACT_NONE = 0, ACT_LEAKY = 1, ACT_RELU = 2 };

typedef __attribute__((ext_vector_type(8))) short short8v;
typedef __attribute__((ext_vector_type(4))) float f32x4;

__device__ __forceinline__ float leakyf(float x) { return x > 0.f ? x : 0.01f * x; }

// order-preserving float -> uint encoding for atomicMax
__device__ __forceinline__ unsigned fenc(float f) {
    unsigned u = __float_as_uint(f);
    return (u & 0x80000000u) ? ~u : (u | 0x80000000u);
}
__device__ __forceinline__ float fdec(unsigned u) {
    return (u & 0x80000000u) ? __uint_as_float(u & 0x7FFFFFFFu) : __uint_as_float(~u);
}

// round-to-nearest bf16 (returns low 16 bits)
__device__ __forceinline__ unsigned bf16rtn(float x) {
    unsigned u = __float_as_uint(x);
    return (u + 0x7FFFu + ((u >> 16) & 1u)) >> 16;
}
__device__ __forceinline__ void split8(float4 a, float4 b, short8v& hi, short8v& lo) {
    const float v[8] = {a.x, a.y, a.z, a.w, b.x, b.y, b.z, b.w};
#pragma unroll
    for (int i = 0; i < 8; i++) {
        const unsigned hb = bf16rtn(v[i]);
        const float r = v[i] - __uint_as_float(hb << 16);
        hi[i] = (short)hb;
        lo[i] = (short)bf16rtn(r);
    }
}

// ---------------------------------------------------------------------------
// fp32 GEMM, NC = 128 fixed:  C[r][c] = actOut( A'[r][:] @ B + bias )
//   A' row r = concat( A[idx? idx[r] : r][0:K1], A2[r][0:K-K1] ).
//   B: [K][128] row-major.
// 256 threads, tile 128 rows x 128 cols, micro 8x8, KT=16.
// ---------------------------------------------------------------------------
__global__ __launch_bounds__(256, 2) void gemm_k(
    const float* __restrict__ A, const float* __restrict__ A2,
    const int* __restrict__ idx,
    const float* __restrict__ B, const float* __restrict__ bias,
    float* __restrict__ C, int M, int K, int K1, int actOut)
{
    __shared__ float Xs[16][128];
    __shared__ float Ws[16][128];
    const int t  = threadIdx.x;
    const int tx = t & 15;   // cols tx*8..+7
    const int ty = t >> 4;   // rows ty*8..+7
    const int rowBase = blockIdx.x * 128;

    float acc[8][8];
#pragma unroll
    for (int i = 0; i < 8; i++)
#pragma unroll
        for (int j = 0; j < 8; j++) acc[i][j] = 0.f;

    const int rS = t >> 1;          // 0..127
    const int kS = (t & 1) << 3;    // 0 or 8
    const int K2 = K - K1;

    for (int k0 = 0; k0 < K; k0 += 16) {
        {
            float v[8] = {0.f,0.f,0.f,0.f,0.f,0.f,0.f,0.f};
            const int row = rowBase + rS;
            if (row < M) {
                const int ar = idx ? idx[row] : row;
                const float* __restrict__ a1 = A + (size_t)ar * K1;
                if (((K1 & 3) == 0) && (k0 + kS + 8 <= K1)) {
                    const float4 a = *(const float4*)&a1[k0 + kS];
                    const float4 b = *(const float4*)&a1[k0 + kS + 4];
                    v[0]=a.x; v[1]=a.y; v[2]=a.z; v[3]=a.w;
                    v[4]=b.x; v[5]=b.y; v[6]=b.z; v[7]=b.w;
                } else {
#pragma unroll
                    for (int j = 0; j < 8; j++) {
                        const int k = k0 + kS + j;
                        float x = 0.f;
                        if (k < K1)     x = a1[k];
                        else if (k < K) x = A2[(size_t)row * K2 + (k - K1)];
                        v[j] = x;
                    }
                }
            }
#pragma unroll
            for (int j = 0; j < 8; j++) Xs[kS + j][rS] = v[j];
        }
        {
            const int cc = (t & 31) << 2;
#pragma unroll
            for (int p = 0; p < 2; p++) {
                const int kk = (t >> 5) + p * 8;
                const int k  = k0 + kk;
                float4 wv = make_float4(0.f, 0.f, 0.f, 0.f);
                if (k < K) wv = *(const float4*)&B[(size_t)k * 128 + cc];
                *(float4*)&Ws[kk][cc] = wv;
            }
        }
        __syncthreads();
#pragma unroll
        for (int k = 0; k < 16; k++) {
            const float4 xa = *(const float4*)&Xs[k][ty << 3];
            const float4 xb = *(const float4*)&Xs[k][(ty << 3) + 4];
            const float4 wa = *(const float4*)&Ws[k][tx << 3];
            const float4 wb = *(const float4*)&Ws[k][(tx << 3) + 4];
            const float xs[8] = {xa.x, xa.y, xa.z, xa.w, xb.x, xb.y, xb.z, xb.w};
            const float ws[8] = {wa.x, wa.y, wa.z, wa.w, wb.x, wb.y, wb.z, wb.w};
#pragma unroll
            for (int i = 0; i < 8; i++)
#pragma unroll
                for (int j = 0; j < 8; j++)
                    acc[i][j] = fmaf(xs[i], ws[j], acc[i][j]);
        }
        __syncthreads();
    }

    const int c0 = tx << 3;
#pragma unroll
    for (int i = 0; i < 8; i++) {
        const int row = rowBase + (ty << 3) + i;
        if (row >= M) continue;
        float o[8];
#pragma unroll
        for (int j = 0; j < 8; j++) {
            float v = acc[i][j] + bias[c0 + j];
            if (actOut == ACT_LEAKY)      v = v > 0.f ? v : 0.01f * v;
            else if (actOut == ACT_RELU)  v = fmaxf(v, 0.f);
            o[j] = v;
        }
        float* __restrict__ cp = C + (size_t)row * 128 + c0;
        *(float4*)cp       = make_float4(o[0], o[1], o[2], o[3]);
        *(float4*)(cp + 4) = make_float4(o[4], o[5], o[6], o[7]);
    }
}

// ---------------------------------------------------------------------------
// W split: [Wih;Whh] fp32 (2x 384x128) -> bf16 hi/lo arrays (same layout)
// ---------------------------------------------------------------------------
__global__ __launch_bounds__(256) void wsplit_k(
    const float* __restrict__ Wih, const float* __restrict__ Whh,
    unsigned short* __restrict__ whi, unsigned short* __restrict__ wlo)
{
    const int i4 = (blockIdx.x * 256 + threadIdx.x) * 4;   // over 2*384*128
    if (i4 >= 98304) return;
    const float* src = (i4 < 49152) ? (Wih + i4) : (Whh + (i4 - 49152));
    const float4 v = *(const float4*)src;
    const float vv[4] = {v.x, v.y, v.z, v.w};
    unsigned short h4[4], l4[4];
#pragma unroll
    for (int i = 0; i < 4; i++) {
        const unsigned hb = bf16rtn(vv[i]);
        const float r = vv[i] - __uint_as_float(hb << 16);
        h4[i] = (unsigned short)hb;
        l4[i] = (unsigned short)bf16rtn(r);
    }
    *(ushort4*)&whi[i4] = make_ushort4(h4[0], h4[1], h4[2], h4[3]);
    *(ushort4*)&wlo[i4] = make_ushort4(l4[0], l4[1], l4[2], l4[3]);
}

// ---------------------------------------------------------------------------
// MFMA GRU GEMM via bf16x3 split:  OUT[r][c] = act(A)[r][:] . W[c][:]
// W pre-split (whi/wlo, [384][128] bf16). 512 threads = 8 waves, block =
// 64 rows x 384 cols. Wave w owns gate-cols {g*128 + w*16 .. +15} for all 3
// gates -> gate triple in-register. A staged to LDS as bf16 hi/lo in
// fragment-linear layout (conflict-free ds_read_b128); ONE barrier total.
// mfma_f32_16x16x32_bf16 fragments: A row=l&15, k=(l>>4)*8+j; B col=l&15,
// same k; D col=l&15, row=(l>>4)*4+reg (m89-verified C/D mapping).
//   GATE=false: gi = elu(A) @ W.T + bias      (A = c)
//   GATE=true : gh = A @ W.T + bias in regs; h = relu(gru(gi, gh, h))
// ---------------------------------------------------------------------------
template <bool GATE>
__global__ __launch_bounds__(512) void gru_mfma_k(
    const float* __restrict__ A, const unsigned short* __restrict__ whi,
    const unsigned short* __restrict__ wlo, const float* __restrict__ bias,
    float* __restrict__ gi, float* __restrict__ h, int M)
{
    __shared__ short lhi[4][4][64][8];   // [rowTile][kChunk][lane][8 bf16]
    __shared__ short llo[4][4][64][8];
    const int t    = threadIdx.x;
    const int lane = t & 63;
    const int w    = t >> 6;             // wave 0..7
    const int rBase = blockIdx.x * 64;

    // ---- stage A split to LDS (fragment-linear) ----
    {
        const int rS = t >> 3, q = t & 7;
        const int row = rBase + rS;
        const int rt = rS >> 4, lrow = rS & 15;
#pragma unroll
        for (int half = 0; half < 2; half++) {
            const int k0 = q * 16 + half * 8;
            const int kc = k0 >> 5;
            const int g  = (k0 & 31) >> 3;
            float4 f0 = make_float4(0.f, 0.f, 0.f, 0.f);
            float4 f1 = make_float4(0.f, 0.f, 0.f, 0.f);
            if (row < M) {
                f0 = *(const float4*)&A[(size_t)row * 128 + k0];
                f1 = *(const float4*)&A[(size_t)row * 128 + k0 + 4];
                if (!GATE) {
                    f0.x = f0.x > 0.f ? f0.x : expm1f(f0.x);
                    f0.y = f0.y > 0.f ? f0.y : expm1f(f0.y);
                    f0.z = f0.z > 0.f ? f0.z : expm1f(f0.z);
                    f0.w = f0.w > 0.f ? f0.w : expm1f(f0.w);
                    f1.x = f1.x > 0.f ? f1.x : expm1f(f1.x);
                    f1.y = f1.y > 0.f ? f1.y : expm1f(f1.y);
                    f1.z = f1.z > 0.f ? f1.z : expm1f(f1.z);
                    f1.w = f1.w > 0.f ? f1.w : expm1f(f1.w);
                }
            }
            short8v h8, l8;
            split8(f0, f1, h8, l8);
            *(short8v*)&lhi[rt][kc][lrow + g * 16][0] = h8;
            *(short8v*)&llo[rt][kc][lrow + g * 16][0] = l8;
        }
    }
    __syncthreads();

    f32x4 acc[3][4];
#pragma unroll
    for (int g = 0; g < 3; g++)
#pragma unroll
        for (int rt = 0; rt < 4; rt++) acc[g][rt] = (f32x4){0.f, 0.f, 0.f, 0.f};

    const int cw   = w * 16 + (lane & 15);   // col within gate space [0,128)
    const int koff = (lane >> 4) * 8;

#pragma unroll
    for (int kc = 0; kc < 4; kc++) {
        short8v bh[3], bl[3];
#pragma unroll
        for (int g = 0; g < 3; g++) {
            const size_t off = (size_t)(g * 128 + cw) * 128 + kc * 32 + koff;
            bh[g] = *(const short8v*)&whi[off];
            bl[g] = *(const short8v*)&wlo[off];
        }
#pragma unroll
        for (int rt = 0; rt < 4; rt++) {
            const short8v ah = *(const short8v*)&lhi[rt][kc][lane][0];
            const short8v al = *(const short8v*)&llo[rt][kc][lane][0];
#pragma unroll
            for (int g = 0; g < 3; g++) {
                acc[g][rt] = __builtin_amdgcn_mfma_f32_16x16x32_bf16(ah, bh[g], acc[g][rt], 0, 0, 0);
                acc[g][rt] = __builtin_amdgcn_mfma_f32_16x16x32_bf16(al, bh[g], acc[g][rt], 0, 0, 0);
                acc[g][rt] = __builtin_amdgcn_mfma_f32_16x16x32_bf16(ah, bl[g], acc[g][rt], 0, 0, 0);
            }
        }
    }

    // ---- epilogue ----
    const float b0 = bias[cw], b1 = bias[128 + cw], b2 = bias[256 + cw];
#pragma unroll
    for (int rt = 0; rt < 4; rt++) {
        const int r0 = rBase + rt * 16 + ((lane >> 4) << 2);
#pragma unroll
        for (int i = 0; i < 4; i++) {
            const int row = r0 + i;
            if (row >= M) continue;
            if (!GATE) {
                float* __restrict__ gp = gi + (size_t)row * 384;
                gp[cw]       = acc[0][rt][i] + b0;
                gp[128 + cw] = acc[1][rt][i] + b1;
                gp[256 + cw] = acc[2][rt][i] + b2;
            } else {
                const float* __restrict__ gp = gi + (size_t)row * 384;
                const float ir = gp[cw], iz = gp[128 + cw], ig = gp[256 + cw];
                const float hv = h[(size_t)row * 128 + cw];
                const float hr = acc[0][rt][i] + b0;
                const float hz = acc[1][rt][i] + b1;
                const float hg = acc[2][rt][i] + b2;
                const float r  = 1.f / (1.f + expf(-(ir + hr)));
                const float z  = 1.f / (1.f + expf(-(iz + hz)));
                const float nn = tanhf(ig + r * hg);
                h[(size_t)row * 128 + cw] = fmaxf((1.f - z) * nn + z * hv, 0.f);
            }
        }
    }
}

// ---------------------------------------------------------------------------
// per-node dual dot: pd[i] = h[i]·wa, ps[i] = h[i]·wb   (one wave per node)
// ---------------------------------------------------------------------------
__global__ __launch_bounds__(256) void node_dots_k(
    const float* __restrict__ h, const float* __restrict__ wa,
    const float* __restrict__ wb, float* __restrict__ pd, float* __restrict__ ps, int n)
{
    const int i = blockIdx.x * 4 + (threadIdx.x >> 6);
    const int l = threadIdx.x & 63;
    if (i >= n) return;
    const float2 hv = *(const float2*)&h[(size_t)i * 128 + l * 2];
    float a = hv.x * wa[l * 2] + hv.y * wa[l * 2 + 1];
    float b = 0.f;
    if (wb) b = hv.x * wb[l * 2] + hv.y * wb[l * 2 + 1];
#pragma unroll
    for (int o = 32; o; o >>= 1) {
        a += __shfl_down(a, o, 64);
        b += __shfl_down(b, o, 64);
    }
    if (l == 0) {
        pd[i] = a;
        if (ps) ps[i] = b;
    }
}

// GetContext edge logits from precomputed pe: lg = leaky(pd[dst]+pe[e]+b2); atomicMax m
__global__ __launch_bounds__(256) void edge_lgc_k(
    const float* __restrict__ pd, const float* __restrict__ pe,
    const float* __restrict__ b2, const int* __restrict__ dst,
    float* __restrict__ lg, unsigned* __restrict__ m_u, int E)
{
    const int e = blockIdx.x * blockDim.x + threadIdx.x;
    if (e >= E) return;
    const int d = dst[e];
    const float v = leakyf(pd[d] + pe[e] + b2[0]);
    lg[e] = v;
    atomicMax(&m_u[d], fenc(v));
}

// e = exp(lg - m[dst]); s[dst] += e
__global__ __launch_bounds__(256) void edge_exp_k(
    float* __restrict__ lg, const unsigned* __restrict__ m_u,
    float* __restrict__ s, const int* __restrict__ dst, int E)
{
    const int e = blockIdx.x * blockDim.x + threadIdx.x;
    if (e >= E) return;
    const int d = dst[e];
    const float ex = expf(lg[e] - fdec(m_u[d]));
    lg[e] = ex;
    atomicAdd(&s[d], ex);
}

// c[dst[e]] += (ee[e]/s[dst[e]]) * rows[e]   (64 lanes x 2 cols) -- GetContext only
__global__ __launch_bounds__(256) void scatter_c_k(
    const float* __restrict__ rows,
    const float* __restrict__ ee, const float* __restrict__ s,
    const int* __restrict__ dst, float* __restrict__ c, int E)
{
    const long long gid = (long long)blockIdx.x * blockDim.x + threadIdx.x;
    const int e = (int)(gid >> 6);
    const int l = (int)(gid & 63);
    if (e >= E) return;
    const int d = dst[e];
    const float a = ee[e] / s[d];
    const float2 v = *(const float2*)&rows[(size_t)e * 128 + l * 2];
    atomicAdd(&c[(size_t)d * 128 + l * 2], a * v.x);
    atomicAdd(&c[(size_t)d * 128 + l * 2 + 1], a * v.y);
}

// ---------------------------------------------------------------------------
// CSR build: histogram -> exclusive scan -> fill
// ---------------------------------------------------------------------------
__global__ __launch_bounds__(256) void hist_k(
    const int* __restrict__ dst, unsigned* __restrict__ cnt, int E)
{
    const int e = blockIdx.x * blockDim.x + threadIdx.x;
    if (e < E) atomicAdd(&cnt[dst[e]], 1u);
}

__global__ __launch_bounds__(1024) void scan_k(
    const unsigned* __restrict__ cnt, int* __restrict__ rp, int N)
{
    __shared__ int wsum[16];
    __shared__ int carry;
    const int t = threadIdx.x, lane = t & 63, wid = t >> 6;
    if (t == 0) carry = 0;
    __syncthreads();
    for (int base = 0; base < N; base += 1024) {
        const int i = base + t;
        const int v = (i < N) ? (int)cnt[i] : 0;
        int x = v;
#pragma unroll
        for (int o = 1; o < 64; o <<= 1) {
            const int y = __shfl_up(x, o, 64);
            if (lane >= o) x += y;
        }
        if (lane == 63) wsum[wid] = x;
        __syncthreads();
        if (wid == 0) {
            const int wv = (lane < 16) ? wsum[lane] : 0;
            int wx = wv;
#pragma unroll
            for (int o = 1; o < 16; o <<= 1) {
                const int y = __shfl_up(wx, o, 64);
                if (lane >= o) wx += y;
            }
            if (lane < 16) wsum[lane] = wx - wv;   // exclusive wave offsets
        }
        __syncthreads();
        const int excl = carry + wsum[wid] + x - v;
        if (i < N) rp[i] = excl;
        __syncthreads();
        if (t == 1023) carry = excl + v;
        __syncthreads();
    }
    if (t == 0) rp[N] = carry;
}

__global__ __launch_bounds__(256) void fill_csr_k(
    const int* __restrict__ dst, int* __restrict__ pos,
    int* __restrict__ eidx, int E)
{
    const int e = blockIdx.x * blockDim.x + threadIdx.x;
    if (e < E) {
        const int p = atomicAdd(&pos[dst[e]], 1);
        eidx[p] = e;
    }
}

// ---------------------------------------------------------------------------
// Fused per-node edge softmax + weighted gather (layers)
// ---------------------------------------------------------------------------
__global__ __launch_bounds__(256) void layer_gather_k(
    const int* __restrict__ rp, const int* __restrict__ eidx,
    const int* __restrict__ src,
    const float* __restrict__ pd, const float* __restrict__ ps,
    const float* __restrict__ bpe,
    const float* __restrict__ hp, float* __restrict__ c, int N)
{
    const int d = blockIdx.x * 4 + (threadIdx.x >> 6);
    const int l = threadIdx.x & 63;
    if (d >= N) return;
    const int beg = rp[d], end = rp[d + 1];
    float acc0 = 0.f, acc1 = 0.f;
    if (beg < end) {
        const float pdd = pd[d];
        const float b   = bpe[0];
        float m = -3.4e38f;
        for (int e = beg + l; e < end; e += 64)
            m = fmaxf(m, leakyf(pdd + ps[src[eidx[e]]] + b));
#pragma unroll
        for (int o = 32; o; o >>= 1) m = fmaxf(m, __shfl_xor(m, o, 64));
        float s = 0.f;
        for (int e = beg + l; e < end; e += 64)
            s += expf(leakyf(pdd + ps[src[eidx[e]]] + b) - m);
#pragma unroll
        for (int o = 32; o; o >>= 1) s += __shfl_xor(s, o, 64);
        const float inv = 1.f / s;
        for (int e = beg; e < end; ++e) {
            const int sr = src[eidx[e]];                 // uniform -> broadcast
            const float a = expf(leakyf(pdd + ps[sr] + b) - m) * inv;
            const float2 v = *(const float2*)&hp[(size_t)sr * 128 + l * 2];
            acc0 = fmaf(a, v.x, acc0);
            acc1 = fmaf(a, v.y, acc1);
        }
    }
    *(float2*)&c[(size_t)d * 128 + l * 2] = make_float2(acc0, acc1);
}

__global__ __launch_bounds__(256) void readout_scatter_k(
    const float* __restrict__ x, const int* __restrict__ gidv,
    float* __restrict__ out, int* __restrict__ counts, int n)
{
    const int i = blockIdx.x * 4 + (threadIdx.x >> 6);
    const int l = threadIdx.x & 63;
    if (i >= n) return;
    const int g = gidv[i];
    const float2 v = *(const float2*)&x[(size_t)i * 128 + l * 2];
    atomicAdd(&out[(size_t)g * 128 + l * 2], v.x);
    atomicAdd(&out[(size_t)g * 128 + l * 2 + 1], v.y);
    if (l == 0) atomicAdd(&counts[g], 1);
}

__global__ __launch_bounds__(256) void readout_div_k(
    float* __restrict__ out, const int* __restrict__ counts, int G)
{
    const int gid = blockIdx.x * blockDim.x + threadIdx.x;
    if (gid >= G * 128) return;
    out[gid] /= fmaxf((float)counts[gid >> 7], 1.f);
}

// ---------------------------------------------------------------------------
extern "C" void kernel_launch(void* const* d_in, const int* in_sizes, int n_in,
                              void* d_out, int out_size, void* d_ws, size_t ws_size,
                              hipStream_t stream)
{
    const float* atom   = (const float*)d_in[0];
    const float* bond   = (const float*)d_in[1];
    const int*   src    = (const int*)d_in[2];
    const int*   dst    = (const int*)d_in[3];
    const int*   ngid   = (const int*)d_in[4];
    const float* W_node = (const float*)d_in[5];
    const float* b_node = (const float*)d_in[6];
    const float* W_e1   = (const float*)d_in[7];
    const float* b_e1   = (const float*)d_in[8];
    const float* W_e2   = (const float*)d_in[9];
    const float* b_e2   = (const float*)d_in[10];
    const float* W_et   = (const float*)d_in[11];
    const float* b_et   = (const float*)d_in[12];
    const float* g0_Wih = (const float*)d_in[13];
    const float* g0_bih = (const float*)d_in[14];
    const float* g0_Whh = (const float*)d_in[15];
    const float* g0_bhh = (const float*)d_in[16];
    const float* Wpe    = (const float*)d_in[17];
    const float* bpe    = (const float*)d_in[18];
    const float* Wpn    = (const float*)d_in[19];
    const float* bpn    = (const float*)d_in[20];
    const float* gWih   = (const float*)d_in[21];
    const float* gbih   = (const float*)d_in[22];
    const float* gWhh   = (const float*)d_in[23];
    const float* gbhh   = (const float*)d_in[24];
    const float* Wr1    = (const float*)d_in[25];
    const float* br1    = (const float*)d_in[26];
    const float* Wr2    = (const float*)d_in[27];
    const float* br2    = (const float*)d_in[28];

    const int N = in_sizes[0] / 74;
    const int E = in_sizes[1] / 12;
    const int G = out_size / 128;
    const int L = in_sizes[18];   // bpe is [L][1]

    char* w = (char*)d_ws;
    auto align256 = [](size_t b) { return (b + 255) & ~(size_t)255; };
    auto alloc = [&](size_t bytes) {
        void* p = (void*)w;
        w += align256(bytes);
        return p;
    };
    // region 1: live across GRU
    float* h    = (float*)alloc((size_t)N * 128 * 4);
    float* c    = (float*)alloc((size_t)N * 128 * 4);
    int*   rp   = (int*)alloc((size_t)(N + 1) * 4);
    int*   posb = (int*)alloc((size_t)N * 4);
    int*   eidx = (int*)alloc((size_t)E * 4);
    int*   cnts = (int*)alloc((size_t)G * 4);
    unsigned short* whib = (unsigned short*)alloc((size_t)2 * 384 * 128 * 2);
    unsigned short* wlob = (unsigned short*)alloc((size_t)2 * 384 * 128 * 2);
    // union region: gi (N*384) overlays {hp, pd, ps, m_u, sden, pe, lg},
    // all dead during the GRU phase.
    char* ubase = w;
    float* gi = (float*)ubase;
    char* u = ubase;
    auto ualloc = [&](size_t bytes) {
        void* p = (void*)u;
        u += align256(bytes);
        return p;
    };
    float*    hp   = (float*)ualloc((size_t)N * 128 * 4);
    float*    pd   = (float*)ualloc((size_t)N * 4);
    float*    ps   = (float*)ualloc((size_t)N * 4);
    unsigned* m_u  = (unsigned*)ualloc((size_t)N * 4);
    float*    sden = (float*)ualloc((size_t)N * 4);
    float*    pe   = (float*)ualloc((size_t)E * 4);
    float*    lg   = (float*)ualloc((size_t)E * 4);
    const size_t usize = (size_t)(u - ubase) > (size_t)N * 384 * 4
                             ? (size_t)(u - ubase) : (size_t)N * 384 * 4;
    const size_t need = (size_t)(ubase - (char*)d_ws) + align256(usize);
    if (need > ws_size) {
        fprintf(stderr, "kernel_launch: ws too small: need %zu, have %zu\n",
                need, ws_size);
        return;
    }
    float* out = (float*)d_out;

    const dim3 blk(256);
    auto g128 = [](int M) { return dim3((unsigned)((M + 127) / 128)); };
    auto g64  = [](int M) { return dim3((unsigned)((M + 63) / 64)); };
    const dim3 gEdge((unsigned)((E + 255) / 256));
    const dim3 gWave4N((unsigned)((N + 3) / 4));
    const int  Ecap = N;           // hp holds up to N rows

    auto run_gru = [&](const float* Wih, const float* bih,
                       const float* Whh, const float* bhh) {
        wsplit_k<<<dim3(96), blk, 0, stream>>>(Wih, Whh, whib, wlob);
        gru_mfma_k<false><<<g64(N), dim3(512), 0, stream>>>(
            c, whib, wlob, bih, gi, nullptr, N);
        gru_mfma_k<true><<<g64(N), dim3(512), 0, stream>>>(
            h, whib + 49152, wlob + 49152, bhh, gi, h, N);
    };

    // ---------------- CSR build (graph static across layers) ----------------
    hipMemsetAsync(m_u, 0, (size_t)N * 4, stream);
    hist_k<<<gEdge, blk, 0, stream>>>(dst, m_u, E);
    scan_k<<<dim3(1), dim3(1024), 0, stream>>>(m_u, rp, N);
    hipMemcpyAsync(posb, rp, (size_t)N * 4, hipMemcpyDeviceToDevice, stream);
    fill_csr_k<<<gEdge, blk, 0, stream>>>(dst, posb, eidx, E);

    // ---------------- GetContext ----------------
    gemm_k<<<g128(N), blk, 0, stream>>>(
        atom, nullptr, nullptr, W_node, b_node, h, N, 74, 74, ACT_LEAKY);
    node_dots_k<<<gWave4N, blk, 0, stream>>>(h, W_e2, nullptr, pd, nullptr, N);
    // pass A: pe[e] = he1[e] . W_e2[128:256]  (chunked, he1 in hp, discarded)
    for (int base = 0; base < E; base += Ecap) {
        const int ec = (E - base) < Ecap ? (E - base) : Ecap;
        gemm_k<<<g128(ec), blk, 0, stream>>>(
            atom, bond + (size_t)base * 12, src + base, W_e1, b_e1, hp,
            ec, 86, 74, ACT_LEAKY);
        node_dots_k<<<dim3((unsigned)((ec + 3) / 4)), blk, 0, stream>>>(
            hp, W_e2 + 128, nullptr, pe + base, nullptr, ec);
    }
    hipMemsetAsync(m_u, 0, (size_t)N * 4, stream);
    hipMemsetAsync(sden, 0, (size_t)N * 4, stream);
    edge_lgc_k<<<gEdge, blk, 0, stream>>>(pd, pe, b_e2, dst, lg, m_u, E);
    edge_exp_k<<<gEdge, blk, 0, stream>>>(lg, m_u, sden, dst, E);
    // pass B: recompute he1 chunk, scatter a*he1 into c; then c = c@W_et + b_et
    hipMemsetAsync(c, 0, (size_t)N * 128 * 4, stream);
    for (int base = 0; base < E; base += Ecap) {
        const int ec = (E - base) < Ecap ? (E - base) : Ecap;
        gemm_k<<<g128(ec), blk, 0, stream>>>(
            atom, bond + (size_t)base * 12, src + base, W_e1, b_e1, hp,
            ec, 86, 74, ACT_LEAKY);
        scatter_c_k<<<dim3((unsigned)(((long long)ec * 64 + 255) / 256)), blk, 0, stream>>>(
            hp, lg + base, sden, dst + base, c, ec);
    }
    gemm_k<<<g128(N), blk, 0, stream>>>(
        c, nullptr, nullptr, W_et, b_et, c, N, 128, 128, ACT_NONE);
    run_gru(g0_Wih, g0_bih, g0_Whh, g0_bhh);

    // ---------------- 11 GNN layers ----------------
    for (int l = 0; l < L; ++l) {
        node_dots_k<<<gWave4N, blk, 0, stream>>>(
            h, Wpe + (size_t)l * 256, Wpe + (size_t)l * 256 + 128, pd, ps, N);
        gemm_k<<<g128(N), blk, 0, stream>>>(
            h, nullptr, nullptr, Wpn + (size_t)l * 16384, bpn + (size_t)l * 128,
            hp, N, 128, 128, ACT_NONE);
        layer_gather_k<<<gWave4N, blk, 0, stream>>>(
            rp, eidx, src, pd, ps, bpe + l, hp, c, N);
        run_gru(gWih + (size_t)l * 49152, gbih + (size_t)l * 384,
                gWhh + (size_t)l * 49152, gbhh + (size_t)l * 384);
    }

    // ---------------- readout ----------------
    gemm_k<<<g128(N), blk, 0, stream>>>(
        h, nullptr, nullptr, Wr1, br1, c, N, 128, 128, ACT_RELU);
    gemm_k<<<g128(N), blk, 0, stream>>>(
        c, nullptr, nullptr, Wr2, br2, hp, N, 128, 128, ACT_NONE);
    hipMemsetAsync(out, 0, (size_t)G * 128 * 4, stream);
    hipMemsetAsync(cnts, 0, (size_t)G * 4, stream);
    readout_scatter_k<<<gWave4N, blk, 0, stream>>>(hp, ngid, out, cnts, N);
    readout_div_k<<<dim3((unsigned)((G * 128 + 255) / 256)), blk, 0, stream>>>(out, cnts, G);

    (void)n_in;
}

// Round 13
// 4958.461 us; speedup vs baseline: 5.5634x; 1.1484x over previous
//
#include <hip/hip_runtime.h>
#include <cstdio>
#include <cstddef>

enum { ACT_NONE = 0, ACT_LEAKY = 1, ACT_RELU = 2 };

typedef __attribute__((ext_vector_type(8))) short short8v;
typedef __attribute__((ext_vector_type(4))) float f32x4;

__device__ __forceinline__ float leakyf(float x) { return x > 0.f ? x : 0.01f * x; }

// order-preserving float -> uint encoding for atomicMax
__device__ __forceinline__ unsigned fenc(float f) {
    unsigned u = __float_as_uint(f);
    return (u & 0x80000000u) ? ~u : (u | 0x80000000u);
}
__device__ __forceinline__ float fdec(unsigned u) {
    return (u & 0x80000000u) ? __uint_as_float(u & 0x7FFFFFFFu) : __uint_as_float(~u);
}

// round-to-nearest bf16 (returns low 16 bits)
__device__ __forceinline__ unsigned bf16rtn(float x) {
    unsigned u = __float_as_uint(x);
    return (u + 0x7FFFu + ((u >> 16) & 1u)) >> 16;
}
__device__ __forceinline__ void split8(float4 a, float4 b, short8v& hi, short8v& lo) {
    const float v[8] = {a.x, a.y, a.z, a.w, b.x, b.y, b.z, b.w};
#pragma unroll
    for (int i = 0; i < 8; i++) {
        const unsigned hb = bf16rtn(v[i]);
        const float r = v[i] - __uint_as_float(hb << 16);
        hi[i] = (short)hb;
        lo[i] = (short)bf16rtn(r);
    }
}

// ---------------------------------------------------------------------------
// fp32 GEMM, NC = 128 fixed (kept for K=74/86 gathered GetContext GEMMs)
// ---------------------------------------------------------------------------
__global__ __launch_bounds__(256, 2) void gemm_k(
    const float* __restrict__ A, const float* __restrict__ A2,
    const int* __restrict__ idx,
    const float* __restrict__ B, const float* __restrict__ bias,
    float* __restrict__ C, int M, int K, int K1, int actOut)
{
    __shared__ float Xs[16][128];
    __shared__ float Ws[16][128];
    const int t  = threadIdx.x;
    const int tx = t & 15;   // cols tx*8..+7
    const int ty = t >> 4;   // rows ty*8..+7
    const int rowBase = blockIdx.x * 128;

    float acc[8][8];
#pragma unroll
    for (int i = 0; i < 8; i++)
#pragma unroll
        for (int j = 0; j < 8; j++) acc[i][j] = 0.f;

    const int rS = t >> 1;          // 0..127
    const int kS = (t & 1) << 3;    // 0 or 8
    const int K2 = K - K1;

    for (int k0 = 0; k0 < K; k0 += 16) {
        {
            float v[8] = {0.f,0.f,0.f,0.f,0.f,0.f,0.f,0.f};
            const int row = rowBase + rS;
            if (row < M) {
                const int ar = idx ? idx[row] : row;
                const float* __restrict__ a1 = A + (size_t)ar * K1;
                if (((K1 & 3) == 0) && (k0 + kS + 8 <= K1)) {
                    const float4 a = *(const float4*)&a1[k0 + kS];
                    const float4 b = *(const float4*)&a1[k0 + kS + 4];
                    v[0]=a.x; v[1]=a.y; v[2]=a.z; v[3]=a.w;
                    v[4]=b.x; v[5]=b.y; v[6]=b.z; v[7]=b.w;
                } else {
#pragma unroll
                    for (int j = 0; j < 8; j++) {
                        const int k = k0 + kS + j;
                        float x = 0.f;
                        if (k < K1)     x = a1[k];
                        else if (k < K) x = A2[(size_t)row * K2 + (k - K1)];
                        v[j] = x;
                    }
                }
            }
#pragma unroll
            for (int j = 0; j < 8; j++) Xs[kS + j][rS] = v[j];
        }
        {
            const int cc = (t & 31) << 2;
#pragma unroll
            for (int p = 0; p < 2; p++) {
                const int kk = (t >> 5) + p * 8;
                const int k  = k0 + kk;
                float4 wv = make_float4(0.f, 0.f, 0.f, 0.f);
                if (k < K) wv = *(const float4*)&B[(size_t)k * 128 + cc];
                *(float4*)&Ws[kk][cc] = wv;
            }
        }
        __syncthreads();
#pragma unroll
        for (int k = 0; k < 16; k++) {
            const float4 xa = *(const float4*)&Xs[k][ty << 3];
            const float4 xb = *(const float4*)&Xs[k][(ty << 3) + 4];
            const float4 wa = *(const float4*)&Ws[k][tx << 3];
            const float4 wb = *(const float4*)&Ws[k][(tx << 3) + 4];
            const float xs[8] = {xa.x, xa.y, xa.z, xa.w, xb.x, xb.y, xb.z, xb.w};
            const float ws[8] = {wa.x, wa.y, wa.z, wa.w, wb.x, wb.y, wb.z, wb.w};
#pragma unroll
            for (int i = 0; i < 8; i++)
#pragma unroll
                for (int j = 0; j < 8; j++)
                    acc[i][j] = fmaf(xs[i], ws[j], acc[i][j]);
        }
        __syncthreads();
    }

    const int c0 = tx << 3;
#pragma unroll
    for (int i = 0; i < 8; i++) {
        const int row = rowBase + (ty << 3) + i;
        if (row >= M) continue;
        float o[8];
#pragma unroll
        for (int j = 0; j < 8; j++) {
            float v = acc[i][j] + bias[c0 + j];
            if (actOut == ACT_LEAKY)      v = v > 0.f ? v : 0.01f * v;
            else if (actOut == ACT_RELU)  v = fmaxf(v, 0.f);
            o[j] = v;
        }
        float* __restrict__ cp = C + (size_t)row * 128 + c0;
        *(float4*)cp       = make_float4(o[0], o[1], o[2], o[3]);
        *(float4*)(cp + 4) = make_float4(o[4], o[5], o[6], o[7]);
    }
}

// ---------------------------------------------------------------------------
// W split: [Wih;Whh] fp32 (2x 384x128, already weight.T layout) -> bf16 hi/lo
// ---------------------------------------------------------------------------
__global__ __launch_bounds__(256) void wsplit_k(
    const float* __restrict__ Wih, const float* __restrict__ Whh,
    unsigned short* __restrict__ whi, unsigned short* __restrict__ wlo)
{
    const int i4 = (blockIdx.x * 256 + threadIdx.x) * 4;   // over 2*384*128
    if (i4 >= 98304) return;
    const float* src = (i4 < 49152) ? (Wih + i4) : (Whh + (i4 - 49152));
    const float4 v = *(const float4*)src;
    const float vv[4] = {v.x, v.y, v.z, v.w};
    unsigned short h4[4], l4[4];
#pragma unroll
    for (int i = 0; i < 4; i++) {
        const unsigned hb = bf16rtn(vv[i]);
        const float r = vv[i] - __uint_as_float(hb << 16);
        h4[i] = (unsigned short)hb;
        l4[i] = (unsigned short)bf16rtn(r);
    }
    *(ushort4*)&whi[i4] = make_ushort4(h4[0], h4[1], h4[2], h4[3]);
    *(ushort4*)&wlo[i4] = make_ushort4(l4[0], l4[1], l4[2], l4[3]);
}

// ---------------------------------------------------------------------------
// W transpose+split: W [K=128][NC=128] row-major -> whi/wlo [col][k] bf16
// (B-fragment layout for MFMA)
// ---------------------------------------------------------------------------
__global__ __launch_bounds__(256) void wsplitT_k(
    const float* __restrict__ W,
    unsigned short* __restrict__ whi, unsigned short* __restrict__ wlo)
{
    const int idx = blockIdx.x * 256 + threadIdx.x;   // 16384
    if (idx >= 16384) return;
    const int k = idx >> 7, col = idx & 127;
    const float v = W[idx];
    const unsigned hb = bf16rtn(v);
    const float r = v - __uint_as_float(hb << 16);
    whi[col * 128 + k] = (unsigned short)hb;
    wlo[col * 128 + k] = (unsigned short)bf16rtn(r);
}

// ---------------------------------------------------------------------------
// MFMA GRU GEMM via bf16x3 split (round-12 verified).
// ---------------------------------------------------------------------------
template <bool GATE>
__global__ __launch_bounds__(512) void gru_mfma_k(
    const float* __restrict__ A, const unsigned short* __restrict__ whi,
    const unsigned short* __restrict__ wlo, const float* __restrict__ bias,
    float* __restrict__ gi, float* __restrict__ h, int M)
{
    __shared__ short lhi[4][4][64][8];   // [rowTile][kChunk][lane][8 bf16]
    __shared__ short llo[4][4][64][8];
    const int t    = threadIdx.x;
    const int lane = t & 63;
    const int w    = t >> 6;             // wave 0..7
    const int rBase = blockIdx.x * 64;

    // ---- stage A split to LDS (fragment-linear) ----
    {
        const int rS = t >> 3, q = t & 7;
        const int row = rBase + rS;
        const int rt = rS >> 4, lrow = rS & 15;
#pragma unroll
        for (int half = 0; half < 2; half++) {
            const int k0 = q * 16 + half * 8;
            const int kc = k0 >> 5;
            const int g  = (k0 & 31) >> 3;
            float4 f0 = make_float4(0.f, 0.f, 0.f, 0.f);
            float4 f1 = make_float4(0.f, 0.f, 0.f, 0.f);
            if (row < M) {
                f0 = *(const float4*)&A[(size_t)row * 128 + k0];
                f1 = *(const float4*)&A[(size_t)row * 128 + k0 + 4];
                if (!GATE) {
                    f0.x = f0.x > 0.f ? f0.x : expm1f(f0.x);
                    f0.y = f0.y > 0.f ? f0.y : expm1f(f0.y);
                    f0.z = f0.z > 0.f ? f0.z : expm1f(f0.z);
                    f0.w = f0.w > 0.f ? f0.w : expm1f(f0.w);
                    f1.x = f1.x > 0.f ? f1.x : expm1f(f1.x);
                    f1.y = f1.y > 0.f ? f1.y : expm1f(f1.y);
                    f1.z = f1.z > 0.f ? f1.z : expm1f(f1.z);
                    f1.w = f1.w > 0.f ? f1.w : expm1f(f1.w);
                }
            }
            short8v h8, l8;
            split8(f0, f1, h8, l8);
            *(short8v*)&lhi[rt][kc][lrow + g * 16][0] = h8;
            *(short8v*)&llo[rt][kc][lrow + g * 16][0] = l8;
        }
    }
    __syncthreads();

    f32x4 acc[3][4];
#pragma unroll
    for (int g = 0; g < 3; g++)
#pragma unroll
        for (int rt = 0; rt < 4; rt++) acc[g][rt] = (f32x4){0.f, 0.f, 0.f, 0.f};

    const int cw   = w * 16 + (lane & 15);   // col within gate space [0,128)
    const int koff = (lane >> 4) * 8;

#pragma unroll
    for (int kc = 0; kc < 4; kc++) {
        short8v bh[3], bl[3];
#pragma unroll
        for (int g = 0; g < 3; g++) {
            const size_t off = (size_t)(g * 128 + cw) * 128 + kc * 32 + koff;
            bh[g] = *(const short8v*)&whi[off];
            bl[g] = *(const short8v*)&wlo[off];
        }
#pragma unroll
        for (int rt = 0; rt < 4; rt++) {
            const short8v ah = *(const short8v*)&lhi[rt][kc][lane][0];
            const short8v al = *(const short8v*)&llo[rt][kc][lane][0];
#pragma unroll
            for (int g = 0; g < 3; g++) {
                acc[g][rt] = __builtin_amdgcn_mfma_f32_16x16x32_bf16(ah, bh[g], acc[g][rt], 0, 0, 0);
                acc[g][rt] = __builtin_amdgcn_mfma_f32_16x16x32_bf16(al, bh[g], acc[g][rt], 0, 0, 0);
                acc[g][rt] = __builtin_amdgcn_mfma_f32_16x16x32_bf16(ah, bl[g], acc[g][rt], 0, 0, 0);
            }
        }
    }

    // ---- epilogue ----
    const float b0 = bias[cw], b1 = bias[128 + cw], b2 = bias[256 + cw];
#pragma unroll
    for (int rt = 0; rt < 4; rt++) {
        const int r0 = rBase + rt * 16 + ((lane >> 4) << 2);
#pragma unroll
        for (int i = 0; i < 4; i++) {
            const int row = r0 + i;
            if (row >= M) continue;
            if (!GATE) {
                float* __restrict__ gp = gi + (size_t)row * 384;
                gp[cw]       = acc[0][rt][i] + b0;
                gp[128 + cw] = acc[1][rt][i] + b1;
                gp[256 + cw] = acc[2][rt][i] + b2;
            } else {
                const float* __restrict__ gp = gi + (size_t)row * 384;
                const float ir = gp[cw], iz = gp[128 + cw], ig = gp[256 + cw];
                const float hv = h[(size_t)row * 128 + cw];
                const float hr = acc[0][rt][i] + b0;
                const float hz = acc[1][rt][i] + b1;
                const float hg = acc[2][rt][i] + b2;
                const float r  = 1.f / (1.f + expf(-(ir + hr)));
                const float z  = 1.f / (1.f + expf(-(iz + hz)));
                const float nn = tanhf(ig + r * hg);
                h[(size_t)row * 128 + cw] = fmaxf((1.f - z) * nn + z * hv, 0.f);
            }
        }
    }
}

// ---------------------------------------------------------------------------
// Single-output MFMA GEMM (K=128, NC=128), bf16x3.  OUT = act(A @ W + bias).
// W pre-split+transposed by wsplitT_k. Same staging/fragments as gru_mfma_k.
// In-place safe (block stages its own 64 rows first, writes in epilogue).
// ---------------------------------------------------------------------------
__global__ __launch_bounds__(512) void mfma128_k(
    const float* __restrict__ A, const unsigned short* __restrict__ whi,
    const unsigned short* __restrict__ wlo, const float* __restrict__ bias,
    float* __restrict__ C, int M, int actOut)
{
    __shared__ short lhi[4][4][64][8];
    __shared__ short llo[4][4][64][8];
    const int t    = threadIdx.x;
    const int lane = t & 63;
    const int w    = t >> 6;
    const int rBase = blockIdx.x * 64;

    {
        const int rS = t >> 3, q = t & 7;
        const int row = rBase + rS;
        const int rt = rS >> 4, lrow = rS & 15;
#pragma unroll
        for (int half = 0; half < 2; half++) {
            const int k0 = q * 16 + half * 8;
            const int kc = k0 >> 5;
            const int g  = (k0 & 31) >> 3;
            float4 f0 = make_float4(0.f, 0.f, 0.f, 0.f);
            float4 f1 = make_float4(0.f, 0.f, 0.f, 0.f);
            if (row < M) {
                f0 = *(const float4*)&A[(size_t)row * 128 + k0];
                f1 = *(const float4*)&A[(size_t)row * 128 + k0 + 4];
            }
            short8v h8, l8;
            split8(f0, f1, h8, l8);
            *(short8v*)&lhi[rt][kc][lrow + g * 16][0] = h8;
            *(short8v*)&llo[rt][kc][lrow + g * 16][0] = l8;
        }
    }
    __syncthreads();

    f32x4 acc[4];
#pragma unroll
    for (int rt = 0; rt < 4; rt++) acc[rt] = (f32x4){0.f, 0.f, 0.f, 0.f};

    const int cw   = w * 16 + (lane & 15);
    const int koff = (lane >> 4) * 8;

#pragma unroll
    for (int kc = 0; kc < 4; kc++) {
        const size_t off = (size_t)cw * 128 + kc * 32 + koff;
        const short8v bh = *(const short8v*)&whi[off];
        const short8v bl = *(const short8v*)&wlo[off];
#pragma unroll
        for (int rt = 0; rt < 4; rt++) {
            const short8v ah = *(const short8v*)&lhi[rt][kc][lane][0];
            const short8v al = *(const short8v*)&llo[rt][kc][lane][0];
            acc[rt] = __builtin_amdgcn_mfma_f32_16x16x32_bf16(ah, bh, acc[rt], 0, 0, 0);
            acc[rt] = __builtin_amdgcn_mfma_f32_16x16x32_bf16(al, bh, acc[rt], 0, 0, 0);
            acc[rt] = __builtin_amdgcn_mfma_f32_16x16x32_bf16(ah, bl, acc[rt], 0, 0, 0);
        }
    }

    const float b0 = bias[cw];
#pragma unroll
    for (int rt = 0; rt < 4; rt++) {
        const int r0 = rBase + rt * 16 + ((lane >> 4) << 2);
#pragma unroll
        for (int i = 0; i < 4; i++) {
            const int row = r0 + i;
            if (row >= M) continue;
            float v = acc[rt][i] + b0;
            if (actOut == ACT_LEAKY)      v = v > 0.f ? v : 0.01f * v;
            else if (actOut == ACT_RELU)  v = fmaxf(v, 0.f);
            C[(size_t)row * 128 + cw] = v;
        }
    }
}

// ---------------------------------------------------------------------------
// per-node dual dot: pd[i] = h[i]·wa, ps[i] = h[i]·wb   (one wave per node)
// ---------------------------------------------------------------------------
__global__ __launch_bounds__(256) void node_dots_k(
    const float* __restrict__ h, const float* __restrict__ wa,
    const float* __restrict__ wb, float* __restrict__ pd, float* __restrict__ ps, int n)
{
    const int i = blockIdx.x * 4 + (threadIdx.x >> 6);
    const int l = threadIdx.x & 63;
    if (i >= n) return;
    const float2 hv = *(const float2*)&h[(size_t)i * 128 + l * 2];
    float a = hv.x * wa[l * 2] + hv.y * wa[l * 2 + 1];
    float b = 0.f;
    if (wb) b = hv.x * wb[l * 2] + hv.y * wb[l * 2 + 1];
#pragma unroll
    for (int o = 32; o; o >>= 1) {
        a += __shfl_down(a, o, 64);
        b += __shfl_down(b, o, 64);
    }
    if (l == 0) {
        pd[i] = a;
        if (ps) ps[i] = b;
    }
}

// GetContext edge logits from precomputed pe: lg = leaky(pd[dst]+pe[e]+b2); atomicMax m
__global__ __launch_bounds__(256) void edge_lgc_k(
    const float* __restrict__ pd, const float* __restrict__ pe,
    const float* __restrict__ b2, const int* __restrict__ dst,
    float* __restrict__ lg, unsigned* __restrict__ m_u, int E)
{
    const int e = blockIdx.x * blockDim.x + threadIdx.x;
    if (e >= E) return;
    const int d = dst[e];
    const float v = leakyf(pd[d] + pe[e] + b2[0]);
    lg[e] = v;
    atomicMax(&m_u[d], fenc(v));
}

// e = exp(lg - m[dst]); s[dst] += e
__global__ __launch_bounds__(256) void edge_exp_k(
    float* __restrict__ lg, const unsigned* __restrict__ m_u,
    float* __restrict__ s, const int* __restrict__ dst, int E)
{
    const int e = blockIdx.x * blockDim.x + threadIdx.x;
    if (e >= E) return;
    const int d = dst[e];
    const float ex = expf(lg[e] - fdec(m_u[d]));
    lg[e] = ex;
    atomicAdd(&s[d], ex);
}

// c[dst[e]] += (ee[e]/s[dst[e]]) * rows[e]   (64 lanes x 2 cols) -- GetContext only
__global__ __launch_bounds__(256) void scatter_c_k(
    const float* __restrict__ rows,
    const float* __restrict__ ee, const float* __restrict__ s,
    const int* __restrict__ dst, float* __restrict__ c, int E)
{
    const long long gid = (long long)blockIdx.x * blockDim.x + threadIdx.x;
    const int e = (int)(gid >> 6);
    const int l = (int)(gid & 63);
    if (e >= E) return;
    const int d = dst[e];
    const float a = ee[e] / s[d];
    const float2 v = *(const float2*)&rows[(size_t)e * 128 + l * 2];
    atomicAdd(&c[(size_t)d * 128 + l * 2], a * v.x);
    atomicAdd(&c[(size_t)d * 128 + l * 2 + 1], a * v.y);
}

// ---------------------------------------------------------------------------
// CSR build: histogram -> exclusive scan -> fill
// ---------------------------------------------------------------------------
__global__ __launch_bounds__(256) void hist_k(
    const int* __restrict__ dst, unsigned* __restrict__ cnt, int E)
{
    const int e = blockIdx.x * blockDim.x + threadIdx.x;
    if (e < E) atomicAdd(&cnt[dst[e]], 1u);
}

__global__ __launch_bounds__(1024) void scan_k(
    const unsigned* __restrict__ cnt, int* __restrict__ rp, int N)
{
    __shared__ int wsum[16];
    __shared__ int carry;
    const int t = threadIdx.x, lane = t & 63, wid = t >> 6;
    if (t == 0) carry = 0;
    __syncthreads();
    for (int base = 0; base < N; base += 1024) {
        const int i = base + t;
        const int v = (i < N) ? (int)cnt[i] : 0;
        int x = v;
#pragma unroll
        for (int o = 1; o < 64; o <<= 1) {
            const int y = __shfl_up(x, o, 64);
            if (lane >= o) x += y;
        }
        if (lane == 63) wsum[wid] = x;
        __syncthreads();
        if (wid == 0) {
            const int wv = (lane < 16) ? wsum[lane] : 0;
            int wx = wv;
#pragma unroll
            for (int o = 1; o < 16; o <<= 1) {
                const int y = __shfl_up(wx, o, 64);
                if (lane >= o) wx += y;
            }
            if (lane < 16) wsum[lane] = wx - wv;   // exclusive wave offsets
        }
        __syncthreads();
        const int excl = carry + wsum[wid] + x - v;
        if (i < N) rp[i] = excl;
        __syncthreads();
        if (t == 1023) carry = excl + v;
        __syncthreads();
    }
    if (t == 0) rp[N] = carry;
}

__global__ __launch_bounds__(256) void fill_csr_k(
    const int* __restrict__ dst, int* __restrict__ pos,
    int* __restrict__ eidx, int E)
{
    const int e = blockIdx.x * blockDim.x + threadIdx.x;
    if (e < E) {
        const int p = atomicAdd(&pos[dst[e]], 1);
        eidx[p] = e;
    }
}

// ---------------------------------------------------------------------------
// Fused per-node edge softmax + weighted gather (layers)
// ---------------------------------------------------------------------------
__global__ __launch_bounds__(256) void layer_gather_k(
    const int* __restrict__ rp, const int* __restrict__ eidx,
    const int* __restrict__ src,
    const float* __restrict__ pd, const float* __restrict__ ps,
    const float* __restrict__ bpe,
    const float* __restrict__ hp, float* __restrict__ c, int N)
{
    const int d = blockIdx.x * 4 + (threadIdx.x >> 6);
    const int l = threadIdx.x & 63;
    if (d >= N) return;
    const int beg = rp[d], end = rp[d + 1];
    float acc0 = 0.f, acc1 = 0.f;
    if (beg < end) {
        const float pdd = pd[d];
        const float b   = bpe[0];
        float m = -3.4e38f;
        for (int e = beg + l; e < end; e += 64)
            m = fmaxf(m, leakyf(pdd + ps[src[eidx[e]]] + b));
#pragma unroll
        for (int o = 32; o; o >>= 1) m = fmaxf(m, __shfl_xor(m, o, 64));
        float s = 0.f;
        for (int e = beg + l; e < end; e += 64)
            s += expf(leakyf(pdd + ps[src[eidx[e]]] + b) - m);
#pragma unroll
        for (int o = 32; o; o >>= 1) s += __shfl_xor(s, o, 64);
        const float inv = 1.f / s;
        for (int e = beg; e < end; ++e) {
            const int sr = src[eidx[e]];                 // uniform -> broadcast
            const float a = expf(leakyf(pdd + ps[sr] + b) - m) * inv;
            const float2 v = *(const float2*)&hp[(size_t)sr * 128 + l * 2];
            acc0 = fmaf(a, v.x, acc0);
            acc1 = fmaf(a, v.y, acc1);
        }
    }
    *(float2*)&c[(size_t)d * 128 + l * 2] = make_float2(acc0, acc1);
}

// segmented mean readout (node_graph_ids sorted): one wave per graph
__global__ __launch_bounds__(256) void readout_mean_k(
    const float* __restrict__ x, const int* __restrict__ grp,
    float* __restrict__ out, int G)
{
    const int g = blockIdx.x * 4 + (threadIdx.x >> 6);
    const int l = threadIdx.x & 63;
    if (g >= G) return;
    const int beg = grp[g], end = grp[g + 1];
    float s0 = 0.f, s1 = 0.f;
    for (int r = beg; r < end; ++r) {
        const float2 v = *(const float2*)&x[(size_t)r * 128 + l * 2];
        s0 += v.x;
        s1 += v.y;
    }
    const float inv = 1.f / fmaxf((float)(end - beg), 1.f);
    *(float2*)&out[(size_t)g * 128 + l * 2] = make_float2(s0 * inv, s1 * inv);
}

// ---------------------------------------------------------------------------
extern "C" void kernel_launch(void* const* d_in, const int* in_sizes, int n_in,
                              void* d_out, int out_size, void* d_ws, size_t ws_size,
                              hipStream_t stream)
{
    const float* atom   = (const float*)d_in[0];
    const float* bond   = (const float*)d_in[1];
    const int*   src    = (const int*)d_in[2];
    const int*   dst    = (const int*)d_in[3];
    const int*   ngid   = (const int*)d_in[4];
    const float* W_node = (const float*)d_in[5];
    const float* b_node = (const float*)d_in[6];
    const float* W_e1   = (const float*)d_in[7];
    const float* b_e1   = (const float*)d_in[8];
    const float* W_e2   = (const float*)d_in[9];
    const float* b_e2   = (const float*)d_in[10];
    const float* W_et   = (const float*)d_in[11];
    const float* b_et   = (const float*)d_in[12];
    const float* g0_Wih = (const float*)d_in[13];
    const float* g0_bih = (const float*)d_in[14];
    const float* g0_Whh = (const float*)d_in[15];
    const float* g0_bhh = (const float*)d_in[16];
    const float* Wpe    = (const float*)d_in[17];
    const float* bpe    = (const float*)d_in[18];
    const float* Wpn    = (const float*)d_in[19];
    const float* bpn    = (const float*)d_in[20];
    const float* gWih   = (const float*)d_in[21];
    const float* gbih   = (const float*)d_in[22];
    const float* gWhh   = (const float*)d_in[23];
    const float* gbhh   = (const float*)d_in[24];
    const float* Wr1    = (const float*)d_in[25];
    const float* br1    = (const float*)d_in[26];
    const float* Wr2    = (const float*)d_in[27];
    const float* br2    = (const float*)d_in[28];

    const int N = in_sizes[0] / 74;
    const int E = in_sizes[1] / 12;
    const int G = out_size / 128;
    const int L = in_sizes[18];   // bpe is [L][1]

    char* w = (char*)d_ws;
    auto align256 = [](size_t b) { return (b + 255) & ~(size_t)255; };
    auto alloc = [&](size_t bytes) {
        void* p = (void*)w;
        w += align256(bytes);
        return p;
    };
    // region 1: live across GRU
    float* h    = (float*)alloc((size_t)N * 128 * 4);
    float* c    = (float*)alloc((size_t)N * 128 * 4);
    int*   rp   = (int*)alloc((size_t)(N + 1) * 4);
    int*   posb = (int*)alloc((size_t)N * 4);
    int*   eidx = (int*)alloc((size_t)E * 4);
    int*   grp  = (int*)alloc((size_t)(G + 1) * 4);
    unsigned short* whib  = (unsigned short*)alloc((size_t)2 * 384 * 128 * 2);
    unsigned short* wlob  = (unsigned short*)alloc((size_t)2 * 384 * 128 * 2);
    unsigned short* wtib  = (unsigned short*)alloc((size_t)128 * 128 * 2);
    unsigned short* wtlob = (unsigned short*)alloc((size_t)128 * 128 * 2);
    // union region: gi (N*384) overlays {hp, pd, ps, m_u, sden, pe, lg},
    // all dead during the GRU phase.
    char* ubase = w;
    float* gi = (float*)ubase;
    char* u = ubase;
    auto ualloc = [&](size_t bytes) {
        void* p = (void*)u;
        u += align256(bytes);
        return p;
    };
    float*    hp   = (float*)ualloc((size_t)N * 128 * 4);
    float*    pd   = (float*)ualloc((size_t)N * 4);
    float*    ps   = (float*)ualloc((size_t)N * 4);
    unsigned* m_u  = (unsigned*)ualloc((size_t)N * 4);
    float*    sden = (float*)ualloc((size_t)N * 4);
    float*    pe   = (float*)ualloc((size_t)E * 4);
    float*    lg   = (float*)ualloc((size_t)E * 4);
    const size_t usize = (size_t)(u - ubase) > (size_t)N * 384 * 4
                             ? (size_t)(u - ubase) : (size_t)N * 384 * 4;
    const size_t need = (size_t)(ubase - (char*)d_ws) + align256(usize);
    if (need > ws_size) {
        fprintf(stderr, "kernel_launch: ws too small: need %zu, have %zu\n",
                need, ws_size);
        return;
    }
    float* out = (float*)d_out;

    const dim3 blk(256);
    auto g128 = [](int M) { return dim3((unsigned)((M + 127) / 128)); };
    auto g64  = [](int M) { return dim3((unsigned)((M + 63) / 64)); };
    const dim3 gEdge((unsigned)((E + 255) / 256));
    const dim3 gWave4N((unsigned)((N + 3) / 4));
    const int  Ecap = N;           // hp holds up to N rows

    auto run_gru = [&](const float* Wih, const float* bih,
                       const float* Whh, const float* bhh) {
        wsplit_k<<<dim3(96), blk, 0, stream>>>(Wih, Whh, whib, wlob);
        gru_mfma_k<false><<<g64(N), dim3(512), 0, stream>>>(
            c, whib, wlob, bih, gi, nullptr, N);
        gru_mfma_k<true><<<g64(N), dim3(512), 0, stream>>>(
            h, whib + 49152, wlob + 49152, bhh, gi, h, N);
    };
    auto run_mfma128 = [&](const float* A, const float* W, const float* bias,
                           float* C, int act) {
        wsplitT_k<<<dim3(64), blk, 0, stream>>>(W, wtib, wtlob);
        mfma128_k<<<g64(N), dim3(512), 0, stream>>>(A, wtib, wtlob, bias, C, N, act);
    };

    // ---------------- CSR build (graph static across layers) ----------------
    hipMemsetAsync(m_u, 0, (size_t)N * 4, stream);
    hist_k<<<gEdge, blk, 0, stream>>>(dst, m_u, E);
    scan_k<<<dim3(1), dim3(1024), 0, stream>>>(m_u, rp, N);
    hipMemcpyAsync(posb, rp, (size_t)N * 4, hipMemcpyDeviceToDevice, stream);
    fill_csr_k<<<gEdge, blk, 0, stream>>>(dst, posb, eidx, E);
    // graph rowptr from sorted ngid
    hipMemsetAsync(m_u, 0, (size_t)G * 4, stream);
    hist_k<<<dim3((unsigned)((N + 255) / 256)), blk, 0, stream>>>(ngid, m_u, N);
    scan_k<<<dim3(1), dim3(1024), 0, stream>>>(m_u, grp, G);

    // ---------------- GetContext ----------------
    gemm_k<<<g128(N), blk, 0, stream>>>(
        atom, nullptr, nullptr, W_node, b_node, h, N, 74, 74, ACT_LEAKY);
    node_dots_k<<<gWave4N, blk, 0, stream>>>(h, W_e2, nullptr, pd, nullptr, N);
    // pass A: pe[e] = he1[e] . W_e2[128:256]  (chunked, he1 in hp, discarded)
    for (int base = 0; base < E; base += Ecap) {
        const int ec = (E - base) < Ecap ? (E - base) : Ecap;
        gemm_k<<<g128(ec), blk, 0, stream>>>(
            atom, bond + (size_t)base * 12, src + base, W_e1, b_e1, hp,
            ec, 86, 74, ACT_LEAKY);
        node_dots_k<<<dim3((unsigned)((ec + 3) / 4)), blk, 0, stream>>>(
            hp, W_e2 + 128, nullptr, pe + base, nullptr, ec);
    }
    hipMemsetAsync(m_u, 0, (size_t)N * 4, stream);
    hipMemsetAsync(sden, 0, (size_t)N * 4, stream);
    edge_lgc_k<<<gEdge, blk, 0, stream>>>(pd, pe, b_e2, dst, lg, m_u, E);
    edge_exp_k<<<gEdge, blk, 0, stream>>>(lg, m_u, sden, dst, E);
    // pass B: recompute he1 chunk, scatter a*he1 into c; then c = c@W_et + b_et
    hipMemsetAsync(c, 0, (size_t)N * 128 * 4, stream);
    for (int base = 0; base < E; base += Ecap) {
        const int ec = (E - base) < Ecap ? (E - base) : Ecap;
        gemm_k<<<g128(ec), blk, 0, stream>>>(
            atom, bond + (size_t)base * 12, src + base, W_e1, b_e1, hp,
            ec, 86, 74, ACT_LEAKY);
        scatter_c_k<<<dim3((unsigned)(((long long)ec * 64 + 255) / 256)), blk, 0, stream>>>(
            hp, lg + base, sden, dst + base, c, ec);
    }
    run_mfma128(c, W_et, b_et, c, ACT_NONE);
    run_gru(g0_Wih, g0_bih, g0_Whh, g0_bhh);

    // ---------------- 11 GNN layers ----------------
    for (int l = 0; l < L; ++l) {
        node_dots_k<<<gWave4N, blk, 0, stream>>>(
            h, Wpe + (size_t)l * 256, Wpe + (size_t)l * 256 + 128, pd, ps, N);
        run_mfma128(h, Wpn + (size_t)l * 16384, bpn + (size_t)l * 128, hp, ACT_NONE);
        layer_gather_k<<<gWave4N, blk, 0, stream>>>(
            rp, eidx, src, pd, ps, bpe + l, hp, c, N);
        run_gru(gWih + (size_t)l * 49152, gbih + (size_t)l * 384,
                gWhh + (size_t)l * 49152, gbhh + (size_t)l * 384);
    }

    // ---------------- readout ----------------
    run_mfma128(h, Wr1, br1, c, ACT_RELU);
    run_mfma128(c, Wr2, br2, hp, ACT_NONE);
    readout_mean_k<<<dim3((unsigned)((G + 3) / 4)), blk, 0, stream>>>(hp, grp, out, G);

    (void)n_in;
}

// Round 14
// 4502.841 us; speedup vs baseline: 6.1263x; 1.1012x over previous
//
#include <hip/hip_runtime.h>
#include <cstdio>
#include <cstddef>

enum { ACT_NONE = 0, ACT_LEAKY = 1, ACT_RELU = 2 };

typedef __attribute__((ext_vector_type(8))) short short8v;
typedef __attribute__((ext_vector_type(4))) float f32x4;

__device__ __forceinline__ float leakyf(float x) { return x > 0.f ? x : 0.01f * x; }

// order-preserving float -> uint encoding for atomicMax
__device__ __forceinline__ unsigned fenc(float f) {
    unsigned u = __float_as_uint(f);
    return (u & 0x80000000u) ? ~u : (u | 0x80000000u);
}
__device__ __forceinline__ float fdec(unsigned u) {
    return (u & 0x80000000u) ? __uint_as_float(u & 0x7FFFFFFFu) : __uint_as_float(~u);
}

// round-to-nearest bf16 (returns low 16 bits)
__device__ __forceinline__ unsigned bf16rtn(float x) {
    unsigned u = __float_as_uint(x);
    return (u + 0x7FFFu + ((u >> 16) & 1u)) >> 16;
}
__device__ __forceinline__ void split8(float4 a, float4 b, short8v& hi, short8v& lo) {
    const float v[8] = {a.x, a.y, a.z, a.w, b.x, b.y, b.z, b.w};
#pragma unroll
    for (int i = 0; i < 8; i++) {
        const unsigned hb = bf16rtn(v[i]);
        const float r = v[i] - __uint_as_float(hb << 16);
        hi[i] = (short)hb;
        lo[i] = (short)bf16rtn(r);
    }
}

// ---------------------------------------------------------------------------
// fp32 GEMM, NC = 128 fixed (kept for K=74/86 gathered GetContext GEMMs)
// ---------------------------------------------------------------------------
__global__ __launch_bounds__(256, 2) void gemm_k(
    const float* __restrict__ A, const float* __restrict__ A2,
    const int* __restrict__ idx,
    const float* __restrict__ B, const float* __restrict__ bias,
    float* __restrict__ C, int M, int K, int K1, int actOut)
{
    __shared__ float Xs[16][128];
    __shared__ float Ws[16][128];
    const int t  = threadIdx.x;
    const int tx = t & 15;   // cols tx*8..+7
    const int ty = t >> 4;   // rows ty*8..+7
    const int rowBase = blockIdx.x * 128;

    float acc[8][8];
#pragma unroll
    for (int i = 0; i < 8; i++)
#pragma unroll
        for (int j = 0; j < 8; j++) acc[i][j] = 0.f;

    const int rS = t >> 1;          // 0..127
    const int kS = (t & 1) << 3;    // 0 or 8
    const int K2 = K - K1;

    for (int k0 = 0; k0 < K; k0 += 16) {
        {
            float v[8] = {0.f,0.f,0.f,0.f,0.f,0.f,0.f,0.f};
            const int row = rowBase + rS;
            if (row < M) {
                const int ar = idx ? idx[row] : row;
                const float* __restrict__ a1 = A + (size_t)ar * K1;
                if (((K1 & 3) == 0) && (k0 + kS + 8 <= K1)) {
                    const float4 a = *(const float4*)&a1[k0 + kS];
                    const float4 b = *(const float4*)&a1[k0 + kS + 4];
                    v[0]=a.x; v[1]=a.y; v[2]=a.z; v[3]=a.w;
                    v[4]=b.x; v[5]=b.y; v[6]=b.z; v[7]=b.w;
                } else {
#pragma unroll
                    for (int j = 0; j < 8; j++) {
                        const int k = k0 + kS + j;
                        float x = 0.f;
                        if (k < K1)     x = a1[k];
                        else if (k < K) x = A2[(size_t)row * K2 + (k - K1)];
                        v[j] = x;
                    }
                }
            }
#pragma unroll
            for (int j = 0; j < 8; j++) Xs[kS + j][rS] = v[j];
        }
        {
            const int cc = (t & 31) << 2;
#pragma unroll
            for (int p = 0; p < 2; p++) {
                const int kk = (t >> 5) + p * 8;
                const int k  = k0 + kk;
                float4 wv = make_float4(0.f, 0.f, 0.f, 0.f);
                if (k < K) wv = *(const float4*)&B[(size_t)k * 128 + cc];
                *(float4*)&Ws[kk][cc] = wv;
            }
        }
        __syncthreads();
#pragma unroll
        for (int k = 0; k < 16; k++) {
            const float4 xa = *(const float4*)&Xs[k][ty << 3];
            const float4 xb = *(const float4*)&Xs[k][(ty << 3) + 4];
            const float4 wa = *(const float4*)&Ws[k][tx << 3];
            const float4 wb = *(const float4*)&Ws[k][(tx << 3) + 4];
            const float xs[8] = {xa.x, xa.y, xa.z, xa.w, xb.x, xb.y, xb.z, xb.w};
            const float ws[8] = {wa.x, wa.y, wa.z, wa.w, wb.x, wb.y, wb.z, wb.w};
#pragma unroll
            for (int i = 0; i < 8; i++)
#pragma unroll
                for (int j = 0; j < 8; j++)
                    acc[i][j] = fmaf(xs[i], ws[j], acc[i][j]);
        }
        __syncthreads();
    }

    const int c0 = tx << 3;
#pragma unroll
    for (int i = 0; i < 8; i++) {
        const int row = rowBase + (ty << 3) + i;
        if (row >= M) continue;
        float o[8];
#pragma unroll
        for (int j = 0; j < 8; j++) {
            float v = acc[i][j] + bias[c0 + j];
            if (actOut == ACT_LEAKY)      v = v > 0.f ? v : 0.01f * v;
            else if (actOut == ACT_RELU)  v = fmaxf(v, 0.f);
            o[j] = v;
        }
        float* __restrict__ cp = C + (size_t)row * 128 + c0;
        *(float4*)cp       = make_float4(o[0], o[1], o[2], o[3]);
        *(float4*)(cp + 4) = make_float4(o[4], o[5], o[6], o[7]);
    }
}

// ---------------------------------------------------------------------------
// W split: [Wih;Whh] fp32 (2x 384x128, already weight.T layout) -> bf16 hi/lo
// ---------------------------------------------------------------------------
__global__ __launch_bounds__(256) void wsplit_k(
    const float* __restrict__ Wih, const float* __restrict__ Whh,
    unsigned short* __restrict__ whi, unsigned short* __restrict__ wlo)
{
    const int i4 = (blockIdx.x * 256 + threadIdx.x) * 4;   // over 2*384*128
    if (i4 >= 98304) return;
    const float* src = (i4 < 49152) ? (Wih + i4) : (Whh + (i4 - 49152));
    const float4 v = *(const float4*)src;
    const float vv[4] = {v.x, v.y, v.z, v.w};
    unsigned short h4[4], l4[4];
#pragma unroll
    for (int i = 0; i < 4; i++) {
        const unsigned hb = bf16rtn(vv[i]);
        const float r = vv[i] - __uint_as_float(hb << 16);
        h4[i] = (unsigned short)hb;
        l4[i] = (unsigned short)bf16rtn(r);
    }
    *(ushort4*)&whi[i4] = make_ushort4(h4[0], h4[1], h4[2], h4[3]);
    *(ushort4*)&wlo[i4] = make_ushort4(l4[0], l4[1], l4[2], l4[3]);
}

// ---------------------------------------------------------------------------
// W transpose+split: W [K=128][NC=128] row-major -> whi/wlo [col][k] bf16
// ---------------------------------------------------------------------------
__global__ __launch_bounds__(256) void wsplitT_k(
    const float* __restrict__ W,
    unsigned short* __restrict__ whi, unsigned short* __restrict__ wlo)
{
    const int idx = blockIdx.x * 256 + threadIdx.x;   // 16384
    if (idx >= 16384) return;
    const int k = idx >> 7, col = idx & 127;
    const float v = W[idx];
    const unsigned hb = bf16rtn(v);
    const float r = v - __uint_as_float(hb << 16);
    whi[col * 128 + k] = (unsigned short)hb;
    wlo[col * 128 + k] = (unsigned short)bf16rtn(r);
}

// ---------------------------------------------------------------------------
// FUSED GRU via bf16x3 MFMA. One launch per stage; gi never touches HBM.
// Combined-accumulator trick: gates r,z need only (ir+hr),(iz+hz) -> run the
// Wih pass on staged elu(c), barrier, re-stage h into the SAME LDS, run the
// Whh pass accumulating r,z into the SAME MFMA accs; only ig,hg separate.
// Acc = 16 f32x4 (AGPR). 512 thr, 64 rows/block, wave w owns gate-cols
// w*16..+15 of all gates. whi/wlo = [Wih(384);Whh(384)][128] bf16 hi/lo.
// In-place safe on h: block stages its own rows, writes in epilogue.
// ---------------------------------------------------------------------------
__global__ __launch_bounds__(512) void gru_fused_mfma_k(
    const float* __restrict__ cbuf, const unsigned short* __restrict__ whi,
    const unsigned short* __restrict__ wlo, const float* __restrict__ bih,
    const float* __restrict__ bhh, float* __restrict__ h, int M)
{
    __shared__ short lhi[4][4][64][8];   // [rowTile][kChunk][lane][8 bf16]
    __shared__ short llo[4][4][64][8];
    const int t    = threadIdx.x;
    const int lane = t & 63;
    const int w    = t >> 6;
    const int rBase = blockIdx.x * 64;

    const int sRS = t >> 3, sQ = t & 7;
    const int sRow = rBase + sRS;
    const int sRT = sRS >> 4, sLrow = sRS & 15;

    auto stage = [&](const float* __restrict__ A, bool doElu) {
#pragma unroll
        for (int half = 0; half < 2; half++) {
            const int k0 = sQ * 16 + half * 8;
            const int kc = k0 >> 5;
            const int g  = (k0 & 31) >> 3;
            float4 f0 = make_float4(0.f, 0.f, 0.f, 0.f);
            float4 f1 = make_float4(0.f, 0.f, 0.f, 0.f);
            if (sRow < M) {
                f0 = *(const float4*)&A[(size_t)sRow * 128 + k0];
                f1 = *(const float4*)&A[(size_t)sRow * 128 + k0 + 4];
                if (doElu) {
                    f0.x = f0.x > 0.f ? f0.x : expm1f(f0.x);
                    f0.y = f0.y > 0.f ? f0.y : expm1f(f0.y);
                    f0.z = f0.z > 0.f ? f0.z : expm1f(f0.z);
                    f0.w = f0.w > 0.f ? f0.w : expm1f(f0.w);
                    f1.x = f1.x > 0.f ? f1.x : expm1f(f1.x);
                    f1.y = f1.y > 0.f ? f1.y : expm1f(f1.y);
                    f1.z = f1.z > 0.f ? f1.z : expm1f(f1.z);
                    f1.w = f1.w > 0.f ? f1.w : expm1f(f1.w);
                }
            }
            short8v h8, l8;
            split8(f0, f1, h8, l8);
            *(short8v*)&lhi[sRT][kc][sLrow + g * 16][0] = h8;
            *(short8v*)&llo[sRT][kc][sLrow + g * 16][0] = l8;
        }
    };

    f32x4 accr[4], accz[4], accig[4], acchg[4];
#pragma unroll
    for (int rt = 0; rt < 4; rt++) {
        accr[rt]  = (f32x4){0.f, 0.f, 0.f, 0.f};
        accz[rt]  = (f32x4){0.f, 0.f, 0.f, 0.f};
        accig[rt] = (f32x4){0.f, 0.f, 0.f, 0.f};
        acchg[rt] = (f32x4){0.f, 0.f, 0.f, 0.f};
    }

    const int cw   = w * 16 + (lane & 15);   // gate-col [0,128)
    const int koff = (lane >> 4) * 8;

    // ---- pass 1: elu(c) @ Wih.T ----
    stage(cbuf, true);
    __syncthreads();
#pragma unroll
    for (int kc = 0; kc < 4; kc++) {
        short8v bh[3], bl[3];
#pragma unroll
        for (int g = 0; g < 3; g++) {
            const size_t off = (size_t)(g * 128 + cw) * 128 + kc * 32 + koff;
            bh[g] = *(const short8v*)&whi[off];
            bl[g] = *(const short8v*)&wlo[off];
        }
#pragma unroll
        for (int rt = 0; rt < 4; rt++) {
            const short8v ah = *(const short8v*)&lhi[rt][kc][lane][0];
            const short8v al = *(const short8v*)&llo[rt][kc][lane][0];
            accr[rt]  = __builtin_amdgcn_mfma_f32_16x16x32_bf16(ah, bh[0], accr[rt], 0, 0, 0);
            accr[rt]  = __builtin_amdgcn_mfma_f32_16x16x32_bf16(al, bh[0], accr[rt], 0, 0, 0);
            accr[rt]  = __builtin_amdgcn_mfma_f32_16x16x32_bf16(ah, bl[0], accr[rt], 0, 0, 0);
            accz[rt]  = __builtin_amdgcn_mfma_f32_16x16x32_bf16(ah, bh[1], accz[rt], 0, 0, 0);
            accz[rt]  = __builtin_amdgcn_mfma_f32_16x16x32_bf16(al, bh[1], accz[rt], 0, 0, 0);
            accz[rt]  = __builtin_amdgcn_mfma_f32_16x16x32_bf16(ah, bl[1], accz[rt], 0, 0, 0);
            accig[rt] = __builtin_amdgcn_mfma_f32_16x16x32_bf16(ah, bh[2], accig[rt], 0, 0, 0);
            accig[rt] = __builtin_amdgcn_mfma_f32_16x16x32_bf16(al, bh[2], accig[rt], 0, 0, 0);
            accig[rt] = __builtin_amdgcn_mfma_f32_16x16x32_bf16(ah, bl[2], accig[rt], 0, 0, 0);
        }
    }
    __syncthreads();   // all waves done reading LDS before re-stage

    // ---- pass 2: h @ Whh.T (r,z accumulate into same accs) ----
    stage(h, false);
    __syncthreads();
#pragma unroll
    for (int kc = 0; kc < 4; kc++) {
        short8v bh[3], bl[3];
#pragma unroll
        for (int g = 0; g < 3; g++) {
            const size_t off = (size_t)(384 + g * 128 + cw) * 128 + kc * 32 + koff;
            bh[g] = *(const short8v*)&whi[off];
            bl[g] = *(const short8v*)&wlo[off];
        }
#pragma unroll
        for (int rt = 0; rt < 4; rt++) {
            const short8v ah = *(const short8v*)&lhi[rt][kc][lane][0];
            const short8v al = *(const short8v*)&llo[rt][kc][lane][0];
            accr[rt]  = __builtin_amdgcn_mfma_f32_16x16x32_bf16(ah, bh[0], accr[rt], 0, 0, 0);
            accr[rt]  = __builtin_amdgcn_mfma_f32_16x16x32_bf16(al, bh[0], accr[rt], 0, 0, 0);
            accr[rt]  = __builtin_amdgcn_mfma_f32_16x16x32_bf16(ah, bl[0], accr[rt], 0, 0, 0);
            accz[rt]  = __builtin_amdgcn_mfma_f32_16x16x32_bf16(ah, bh[1], accz[rt], 0, 0, 0);
            accz[rt]  = __builtin_amdgcn_mfma_f32_16x16x32_bf16(al, bh[1], accz[rt], 0, 0, 0);
            accz[rt]  = __builtin_amdgcn_mfma_f32_16x16x32_bf16(ah, bl[1], accz[rt], 0, 0, 0);
            acchg[rt] = __builtin_amdgcn_mfma_f32_16x16x32_bf16(ah, bh[2], acchg[rt], 0, 0, 0);
            acchg[rt] = __builtin_amdgcn_mfma_f32_16x16x32_bf16(al, bh[2], acchg[rt], 0, 0, 0);
            acchg[rt] = __builtin_amdgcn_mfma_f32_16x16x32_bf16(ah, bl[2], acchg[rt], 0, 0, 0);
        }
    }

    // ---- gate epilogue ----
    const float br_  = bih[cw] + bhh[cw];
    const float bz_  = bih[128 + cw] + bhh[128 + cw];
    const float big_ = bih[256 + cw];
    const float bhg_ = bhh[256 + cw];
#pragma unroll
    for (int rt = 0; rt < 4; rt++) {
        const int r0 = rBase + rt * 16 + ((lane >> 4) << 2);
#pragma unroll
        for (int i = 0; i < 4; i++) {
            const int row = r0 + i;
            if (row >= M) continue;
            const float hv = h[(size_t)row * 128 + cw];
            const float r  = 1.f / (1.f + expf(-(accr[rt][i] + br_)));
            const float z  = 1.f / (1.f + expf(-(accz[rt][i] + bz_)));
            const float nn = tanhf(accig[rt][i] + big_ + r * (acchg[rt][i] + bhg_));
            h[(size_t)row * 128 + cw] = fmaxf((1.f - z) * nn + z * hv, 0.f);
        }
    }
}

// ---------------------------------------------------------------------------
// Single-output MFMA GEMM (K=128, NC=128), bf16x3 (round-13 verified).
// ---------------------------------------------------------------------------
__global__ __launch_bounds__(512) void mfma128_k(
    const float* __restrict__ A, const unsigned short* __restrict__ whi,
    const unsigned short* __restrict__ wlo, const float* __restrict__ bias,
    float* __restrict__ C, int M, int actOut)
{
    __shared__ short lhi[4][4][64][8];
    __shared__ short llo[4][4][64][8];
    const int t    = threadIdx.x;
    const int lane = t & 63;
    const int w    = t >> 6;
    const int rBase = blockIdx.x * 64;

    {
        const int rS = t >> 3, q = t & 7;
        const int row = rBase + rS;
        const int rt = rS >> 4, lrow = rS & 15;
#pragma unroll
        for (int half = 0; half < 2; half++) {
            const int k0 = q * 16 + half * 8;
            const int kc = k0 >> 5;
            const int g  = (k0 & 31) >> 3;
            float4 f0 = make_float4(0.f, 0.f, 0.f, 0.f);
            float4 f1 = make_float4(0.f, 0.f, 0.f, 0.f);
            if (row < M) {
                f0 = *(const float4*)&A[(size_t)row * 128 + k0];
                f1 = *(const float4*)&A[(size_t)row * 128 + k0 + 4];
            }
            short8v h8, l8;
            split8(f0, f1, h8, l8);
            *(short8v*)&lhi[rt][kc][lrow + g * 16][0] = h8;
            *(short8v*)&llo[rt][kc][lrow + g * 16][0] = l8;
        }
    }
    __syncthreads();

    f32x4 acc[4];
#pragma unroll
    for (int rt = 0; rt < 4; rt++) acc[rt] = (f32x4){0.f, 0.f, 0.f, 0.f};

    const int cw   = w * 16 + (lane & 15);
    const int koff = (lane >> 4) * 8;

#pragma unroll
    for (int kc = 0; kc < 4; kc++) {
        const size_t off = (size_t)cw * 128 + kc * 32 + koff;
        const short8v bh = *(const short8v*)&whi[off];
        const short8v bl = *(const short8v*)&wlo[off];
#pragma unroll
        for (int rt = 0; rt < 4; rt++) {
            const short8v ah = *(const short8v*)&lhi[rt][kc][lane][0];
            const short8v al = *(const short8v*)&llo[rt][kc][lane][0];
            acc[rt] = __builtin_amdgcn_mfma_f32_16x16x32_bf16(ah, bh, acc[rt], 0, 0, 0);
            acc[rt] = __builtin_amdgcn_mfma_f32_16x16x32_bf16(al, bh, acc[rt], 0, 0, 0);
            acc[rt] = __builtin_amdgcn_mfma_f32_16x16x32_bf16(ah, bl, acc[rt], 0, 0, 0);
        }
    }

    const float b0 = bias[cw];
#pragma unroll
    for (int rt = 0; rt < 4; rt++) {
        const int r0 = rBase + rt * 16 + ((lane >> 4) << 2);
#pragma unroll
        for (int i = 0; i < 4; i++) {
            const int row = r0 + i;
            if (row >= M) continue;
            float v = acc[rt][i] + b0;
            if (actOut == ACT_LEAKY)      v = v > 0.f ? v : 0.01f * v;
            else if (actOut == ACT_RELU)  v = fmaxf(v, 0.f);
            C[(size_t)row * 128 + cw] = v;
        }
    }
}

// ---------------------------------------------------------------------------
// per-node dual dot: pd[i] = h[i]·wa, ps[i] = h[i]·wb   (one wave per node)
// ---------------------------------------------------------------------------
__global__ __launch_bounds__(256) void node_dots_k(
    const float* __restrict__ h, const float* __restrict__ wa,
    const float* __restrict__ wb, float* __restrict__ pd, float* __restrict__ ps, int n)
{
    const int i = blockIdx.x * 4 + (threadIdx.x >> 6);
    const int l = threadIdx.x & 63;
    if (i >= n) return;
    const float2 hv = *(const float2*)&h[(size_t)i * 128 + l * 2];
    float a = hv.x * wa[l * 2] + hv.y * wa[l * 2 + 1];
    float b = 0.f;
    if (wb) b = hv.x * wb[l * 2] + hv.y * wb[l * 2 + 1];
#pragma unroll
    for (int o = 32; o; o >>= 1) {
        a += __shfl_down(a, o, 64);
        b += __shfl_down(b, o, 64);
    }
    if (l == 0) {
        pd[i] = a;
        if (ps) ps[i] = b;
    }
}

// GetContext edge logits from precomputed pe: lg = leaky(pd[dst]+pe[e]+b2); atomicMax m
__global__ __launch_bounds__(256) void edge_lgc_k(
    const float* __restrict__ pd, const float* __restrict__ pe,
    const float* __restrict__ b2, const int* __restrict__ dst,
    float* __restrict__ lg, unsigned* __restrict__ m_u, int E)
{
    const int e = blockIdx.x * blockDim.x + threadIdx.x;
    if (e >= E) return;
    const int d = dst[e];
    const float v = leakyf(pd[d] + pe[e] + b2[0]);
    lg[e] = v;
    atomicMax(&m_u[d], fenc(v));
}

// e = exp(lg - m[dst]); s[dst] += e
__global__ __launch_bounds__(256) void edge_exp_k(
    float* __restrict__ lg, const unsigned* __restrict__ m_u,
    float* __restrict__ s, const int* __restrict__ dst, int E)
{
    const int e = blockIdx.x * blockDim.x + threadIdx.x;
    if (e >= E) return;
    const int d = dst[e];
    const float ex = expf(lg[e] - fdec(m_u[d]));
    lg[e] = ex;
    atomicAdd(&s[d], ex);
}

// c[dst[e]] += (ee[e]/s[dst[e]]) * rows[e]   (64 lanes x 2 cols) -- GetContext only
__global__ __launch_bounds__(256) void scatter_c_k(
    const float* __restrict__ rows,
    const float* __restrict__ ee, const float* __restrict__ s,
    const int* __restrict__ dst, float* __restrict__ c, int E)
{
    const long long gid = (long long)blockIdx.x * blockDim.x + threadIdx.x;
    const int e = (int)(gid >> 6);
    const int l = (int)(gid & 63);
    if (e >= E) return;
    const int d = dst[e];
    const float a = ee[e] / s[d];
    const float2 v = *(const float2*)&rows[(size_t)e * 128 + l * 2];
    atomicAdd(&c[(size_t)d * 128 + l * 2], a * v.x);
    atomicAdd(&c[(size_t)d * 128 + l * 2 + 1], a * v.y);
}

// ---------------------------------------------------------------------------
// CSR build: histogram -> exclusive scan -> fill
// ---------------------------------------------------------------------------
__global__ __launch_bounds__(256) void hist_k(
    const int* __restrict__ dst, unsigned* __restrict__ cnt, int E)
{
    const int e = blockIdx.x * blockDim.x + threadIdx.x;
    if (e < E) atomicAdd(&cnt[dst[e]], 1u);
}

__global__ __launch_bounds__(1024) void scan_k(
    const unsigned* __restrict__ cnt, int* __restrict__ rp, int N)
{
    __shared__ int wsum[16];
    __shared__ int carry;
    const int t = threadIdx.x, lane = t & 63, wid = t >> 6;
    if (t == 0) carry = 0;
    __syncthreads();
    for (int base = 0; base < N; base += 1024) {
        const int i = base + t;
        const int v = (i < N) ? (int)cnt[i] : 0;
        int x = v;
#pragma unroll
        for (int o = 1; o < 64; o <<= 1) {
            const int y = __shfl_up(x, o, 64);
            if (lane >= o) x += y;
        }
        if (lane == 63) wsum[wid] = x;
        __syncthreads();
        if (wid == 0) {
            const int wv = (lane < 16) ? wsum[lane] : 0;
            int wx = wv;
#pragma unroll
            for (int o = 1; o < 16; o <<= 1) {
                const int y = __shfl_up(wx, o, 64);
                if (lane >= o) wx += y;
            }
            if (lane < 16) wsum[lane] = wx - wv;   // exclusive wave offsets
        }
        __syncthreads();
        const int excl = carry + wsum[wid] + x - v;
        if (i < N) rp[i] = excl;
        __syncthreads();
        if (t == 1023) carry = excl + v;
        __syncthreads();
    }
    if (t == 0) rp[N] = carry;
}

__global__ __launch_bounds__(256) void fill_csr_k(
    const int* __restrict__ dst, int* __restrict__ pos,
    int* __restrict__ eidx, int E)
{
    const int e = blockIdx.x * blockDim.x + threadIdx.x;
    if (e < E) {
        const int p = atomicAdd(&pos[dst[e]], 1);
        eidx[p] = e;
    }
}

// ---------------------------------------------------------------------------
// Fused per-node edge softmax + weighted gather (layers)
// ---------------------------------------------------------------------------
__global__ __launch_bounds__(256) void layer_gather_k(
    const int* __restrict__ rp, const int* __restrict__ eidx,
    const int* __restrict__ src,
    const float* __restrict__ pd, const float* __restrict__ ps,
    const float* __restrict__ bpe,
    const float* __restrict__ hp, float* __restrict__ c, int N)
{
    const int d = blockIdx.x * 4 + (threadIdx.x >> 6);
    const int l = threadIdx.x & 63;
    if (d >= N) return;
    const int beg = rp[d], end = rp[d + 1];
    float acc0 = 0.f, acc1 = 0.f;
    if (beg < end) {
        const float pdd = pd[d];
        const float b   = bpe[0];
        float m = -3.4e38f;
        for (int e = beg + l; e < end; e += 64)
            m = fmaxf(m, leakyf(pdd + ps[src[eidx[e]]] + b));
#pragma unroll
        for (int o = 32; o; o >>= 1) m = fmaxf(m, __shfl_xor(m, o, 64));
        float s = 0.f;
        for (int e = beg + l; e < end; e += 64)
            s += expf(leakyf(pdd + ps[src[eidx[e]]] + b) - m);
#pragma unroll
        for (int o = 32; o; o >>= 1) s += __shfl_xor(s, o, 64);
        const float inv = 1.f / s;
        for (int e = beg; e < end; ++e) {
            const int sr = src[eidx[e]];                 // uniform -> broadcast
            const float a = expf(leakyf(pdd + ps[sr] + b) - m) * inv;
            const float2 v = *(const float2*)&hp[(size_t)sr * 128 + l * 2];
            acc0 = fmaf(a, v.x, acc0);
            acc1 = fmaf(a, v.y, acc1);
        }
    }
    *(float2*)&c[(size_t)d * 128 + l * 2] = make_float2(acc0, acc1);
}

// segmented mean readout (node_graph_ids sorted): one wave per graph
__global__ __launch_bounds__(256) void readout_mean_k(
    const float* __restrict__ x, const int* __restrict__ grp,
    float* __restrict__ out, int G)
{
    const int g = blockIdx.x * 4 + (threadIdx.x >> 6);
    const int l = threadIdx.x & 63;
    if (g >= G) return;
    const int beg = grp[g], end = grp[g + 1];
    float s0 = 0.f, s1 = 0.f;
    for (int r = beg; r < end; ++r) {
        const float2 v = *(const float2*)&x[(size_t)r * 128 + l * 2];
        s0 += v.x;
        s1 += v.y;
    }
    const float inv = 1.f / fmaxf((float)(end - beg), 1.f);
    *(float2*)&out[(size_t)g * 128 + l * 2] = make_float2(s0 * inv, s1 * inv);
}

// ---------------------------------------------------------------------------
extern "C" void kernel_launch(void* const* d_in, const int* in_sizes, int n_in,
                              void* d_out, int out_size, void* d_ws, size_t ws_size,
                              hipStream_t stream)
{
    const float* atom   = (const float*)d_in[0];
    const float* bond   = (const float*)d_in[1];
    const int*   src    = (const int*)d_in[2];
    const int*   dst    = (const int*)d_in[3];
    const int*   ngid   = (const int*)d_in[4];
    const float* W_node = (const float*)d_in[5];
    const float* b_node = (const float*)d_in[6];
    const float* W_e1   = (const float*)d_in[7];
    const float* b_e1   = (const float*)d_in[8];
    const float* W_e2   = (const float*)d_in[9];
    const float* b_e2   = (const float*)d_in[10];
    const float* W_et   = (const float*)d_in[11];
    const float* b_et   = (const float*)d_in[12];
    const float* g0_Wih = (const float*)d_in[13];
    const float* g0_bih = (const float*)d_in[14];
    const float* g0_Whh = (const float*)d_in[15];
    const float* g0_bhh = (const float*)d_in[16];
    const float* Wpe    = (const float*)d_in[17];
    const float* bpe    = (const float*)d_in[18];
    const float* Wpn    = (const float*)d_in[19];
    const float* bpn    = (const float*)d_in[20];
    const float* gWih   = (const float*)d_in[21];
    const float* gbih   = (const float*)d_in[22];
    const float* gWhh   = (const float*)d_in[23];
    const float* gbhh   = (const float*)d_in[24];
    const float* Wr1    = (const float*)d_in[25];
    const float* br1    = (const float*)d_in[26];
    const float* Wr2    = (const float*)d_in[27];
    const float* br2    = (const float*)d_in[28];

    const int N = in_sizes[0] / 74;
    const int E = in_sizes[1] / 12;
    const int G = out_size / 128;
    const int L = in_sizes[18];   // bpe is [L][1]

    char* w = (char*)d_ws;
    auto align256 = [](size_t b) { return (b + 255) & ~(size_t)255; };
    auto alloc = [&](size_t bytes) {
        void* p = (void*)w;
        w += align256(bytes);
        return p;
    };
    float*    h    = (float*)alloc((size_t)N * 128 * 4);
    float*    c    = (float*)alloc((size_t)N * 128 * 4);
    float*    hp   = (float*)alloc((size_t)N * 128 * 4);
    int*      rp   = (int*)alloc((size_t)(N + 1) * 4);
    int*      posb = (int*)alloc((size_t)N * 4);
    int*      eidx = (int*)alloc((size_t)E * 4);
    int*      grp  = (int*)alloc((size_t)(G + 1) * 4);
    unsigned short* whib  = (unsigned short*)alloc((size_t)2 * 384 * 128 * 2);
    unsigned short* wlob  = (unsigned short*)alloc((size_t)2 * 384 * 128 * 2);
    unsigned short* wtib  = (unsigned short*)alloc((size_t)128 * 128 * 2);
    unsigned short* wtlob = (unsigned short*)alloc((size_t)128 * 128 * 2);
    float*    pd   = (float*)alloc((size_t)N * 4);
    float*    ps   = (float*)alloc((size_t)N * 4);
    unsigned* m_u  = (unsigned*)alloc((size_t)N * 4);
    float*    sden = (float*)alloc((size_t)N * 4);
    float*    pe   = (float*)alloc((size_t)E * 4);
    float*    lg   = (float*)alloc((size_t)E * 4);
    if ((size_t)(w - (char*)d_ws) > ws_size) {
        fprintf(stderr, "kernel_launch: ws too small: need %zu, have %zu\n",
                (size_t)(w - (char*)d_ws), ws_size);
        return;
    }
    float* out = (float*)d_out;

    const dim3 blk(256);
    auto g128 = [](int M) { return dim3((unsigned)((M + 127) / 128)); };
    auto g64  = [](int M) { return dim3((unsigned)((M + 63) / 64)); };
    const dim3 gEdge((unsigned)((E + 255) / 256));
    const dim3 gWave4N((unsigned)((N + 3) / 4));
    const int  Ecap = N;           // hp holds up to N rows

    auto run_gru = [&](const float* Wih, const float* bih,
                       const float* Whh, const float* bhh) {
        wsplit_k<<<dim3(96), blk, 0, stream>>>(Wih, Whh, whib, wlob);
        gru_fused_mfma_k<<<g64(N), dim3(512), 0, stream>>>(
            c, whib, wlob, bih, bhh, h, N);
    };
    auto run_mfma128 = [&](const float* A, const float* W, const float* bias,
                           float* C, int act) {
        wsplitT_k<<<dim3(64), blk, 0, stream>>>(W, wtib, wtlob);
        mfma128_k<<<g64(N), dim3(512), 0, stream>>>(A, wtib, wtlob, bias, C, N, act);
    };

    // ---------------- CSR build (graph static across layers) ----------------
    hipMemsetAsync(m_u, 0, (size_t)N * 4, stream);
    hist_k<<<gEdge, blk, 0, stream>>>(dst, m_u, E);
    scan_k<<<dim3(1), dim3(1024), 0, stream>>>(m_u, rp, N);
    hipMemcpyAsync(posb, rp, (size_t)N * 4, hipMemcpyDeviceToDevice, stream);
    fill_csr_k<<<gEdge, blk, 0, stream>>>(dst, posb, eidx, E);
    // graph rowptr from sorted ngid
    hipMemsetAsync(m_u, 0, (size_t)G * 4, stream);
    hist_k<<<dim3((unsigned)((N + 255) / 256)), blk, 0, stream>>>(ngid, m_u, N);
    scan_k<<<dim3(1), dim3(1024), 0, stream>>>(m_u, grp, G);

    // ---------------- GetContext ----------------
    gemm_k<<<g128(N), blk, 0, stream>>>(
        atom, nullptr, nullptr, W_node, b_node, h, N, 74, 74, ACT_LEAKY);
    node_dots_k<<<gWave4N, blk, 0, stream>>>(h, W_e2, nullptr, pd, nullptr, N);
    // pass A: pe[e] = he1[e] . W_e2[128:256]  (chunked, he1 in hp, discarded)
    for (int base = 0; base < E; base += Ecap) {
        const int ec = (E - base) < Ecap ? (E - base) : Ecap;
        gemm_k<<<g128(ec), blk, 0, stream>>>(
            atom, bond + (size_t)base * 12, src + base, W_e1, b_e1, hp,
            ec, 86, 74, ACT_LEAKY);
        node_dots_k<<<dim3((unsigned)((ec + 3) / 4)), blk, 0, stream>>>(
            hp, W_e2 + 128, nullptr, pe + base, nullptr, ec);
    }
    hipMemsetAsync(m_u, 0, (size_t)N * 4, stream);
    hipMemsetAsync(sden, 0, (size_t)N * 4, stream);
    edge_lgc_k<<<gEdge, blk, 0, stream>>>(pd, pe, b_e2, dst, lg, m_u, E);
    edge_exp_k<<<gEdge, blk, 0, stream>>>(lg, m_u, sden, dst, E);
    // pass B: recompute he1 chunk, scatter a*he1 into c; then c = c@W_et + b_et
    hipMemsetAsync(c, 0, (size_t)N * 128 * 4, stream);
    for (int base = 0; base < E; base += Ecap) {
        const int ec = (E - base) < Ecap ? (E - base) : Ecap;
        gemm_k<<<g128(ec), blk, 0, stream>>>(
            atom, bond + (size_t)base * 12, src + base, W_e1, b_e1, hp,
            ec, 86, 74, ACT_LEAKY);
        scatter_c_k<<<dim3((unsigned)(((long long)ec * 64 + 255) / 256)), blk, 0, stream>>>(
            hp, lg + base, sden, dst + base, c, ec);
    }
    run_mfma128(c, W_et, b_et, c, ACT_NONE);
    run_gru(g0_Wih, g0_bih, g0_Whh, g0_bhh);

    // ---------------- 11 GNN layers ----------------
    for (int l = 0; l < L; ++l) {
        node_dots_k<<<gWave4N, blk, 0, stream>>>(
            h, Wpe + (size_t)l * 256, Wpe + (size_t)l * 256 + 128, pd, ps, N);
        run_mfma128(h, Wpn + (size_t)l * 16384, bpn + (size_t)l * 128, hp, ACT_NONE);
        layer_gather_k<<<gWave4N, blk, 0, stream>>>(
            rp, eidx, src, pd, ps, bpe + l, hp, c, N);
        run_gru(gWih + (size_t)l * 49152, gbih + (size_t)l * 384,
                gWhh + (size_t)l * 49152, gbhh + (size_t)l * 384);
    }

    // ---------------- readout ----------------
    run_mfma128(h, Wr1, br1, c, ACT_RELU);
    run_mfma128(c, Wr2, br2, hp, ACT_NONE);
    readout_mean_k<<<dim3((unsigned)((G + 3) / 4)), blk, 0, stream>>>(hp, grp, out, G);

    (void)n_in;
}

// Round 15
// 4071.629 us; speedup vs baseline: 6.7751x; 1.1059x over previous
//
#include <hip/hip_runtime.h>
#include <cstdio>
#include <cstddef>

enum { ACT_NONE = 0, ACT_LEAKY = 1, ACT_RELU = 2 };

typedef __attribute__((ext_vector_type(8))) short short8v;
typedef __attribute__((ext_vector_type(4))) float f32x4;

__device__ __forceinline__ float leakyf(float x) { return x > 0.f ? x : 0.01f * x; }

// order-preserving float -> uint encoding for atomicMax
__device__ __forceinline__ unsigned fenc(float f) {
    unsigned u = __float_as_uint(f);
    return (u & 0x80000000u) ? ~u : (u | 0x80000000u);
}
__device__ __forceinline__ float fdec(unsigned u) {
    return (u & 0x80000000u) ? __uint_as_float(u & 0x7FFFFFFFu) : __uint_as_float(~u);
}

// round-to-nearest bf16 (returns low 16 bits)
__device__ __forceinline__ unsigned bf16rtn(float x) {
    unsigned u = __float_as_uint(x);
    return (u + 0x7FFFu + ((u >> 16) & 1u)) >> 16;
}
__device__ __forceinline__ void split8(float4 a, float4 b, short8v& hi, short8v& lo) {
    const float v[8] = {a.x, a.y, a.z, a.w, b.x, b.y, b.z, b.w};
#pragma unroll
    for (int i = 0; i < 8; i++) {
        const unsigned hb = bf16rtn(v[i]);
        const float r = v[i] - __uint_as_float(hb << 16);
        hi[i] = (short)hb;
        lo[i] = (short)bf16rtn(r);
    }
}

// ---------------------------------------------------------------------------
// W split: [Wih;Whh] fp32 (2x 384x128, weight.T layout) -> bf16 hi/lo
// ---------------------------------------------------------------------------
__global__ __launch_bounds__(256) void wsplit_k(
    const float* __restrict__ Wih, const float* __restrict__ Whh,
    unsigned short* __restrict__ whi, unsigned short* __restrict__ wlo)
{
    const int i4 = (blockIdx.x * 256 + threadIdx.x) * 4;   // over 2*384*128
    if (i4 >= 98304) return;
    const float* src = (i4 < 49152) ? (Wih + i4) : (Whh + (i4 - 49152));
    const float4 v = *(const float4*)src;
    const float vv[4] = {v.x, v.y, v.z, v.w};
    unsigned short h4[4], l4[4];
#pragma unroll
    for (int i = 0; i < 4; i++) {
        const unsigned hb = bf16rtn(vv[i]);
        const float r = vv[i] - __uint_as_float(hb << 16);
        h4[i] = (unsigned short)hb;
        l4[i] = (unsigned short)bf16rtn(r);
    }
    *(ushort4*)&whi[i4] = make_ushort4(h4[0], h4[1], h4[2], h4[3]);
    *(ushort4*)&wlo[i4] = make_ushort4(l4[0], l4[1], l4[2], l4[3]);
}

// ---------------------------------------------------------------------------
// W transpose+split: W [K=128][NC=128] row-major -> whi/wlo [col][128k] bf16
// ---------------------------------------------------------------------------
__global__ __launch_bounds__(256) void wsplitT_k(
    const float* __restrict__ W,
    unsigned short* __restrict__ whi, unsigned short* __restrict__ wlo)
{
    const int idx = blockIdx.x * 256 + threadIdx.x;   // 16384
    if (idx >= 16384) return;
    const int k = idx >> 7, col = idx & 127;
    const float v = W[idx];
    const unsigned hb = bf16rtn(v);
    const float r = v - __uint_as_float(hb << 16);
    whi[col * 128 + k] = (unsigned short)hb;
    wlo[col * 128 + k] = (unsigned short)bf16rtn(r);
}

// ---------------------------------------------------------------------------
// W transpose+split for K<=96: W [K][128] -> [col][96] bf16, zero-padded tail
// ---------------------------------------------------------------------------
__global__ __launch_bounds__(256) void wsplitT96_k(
    const float* __restrict__ W,
    unsigned short* __restrict__ whi, unsigned short* __restrict__ wlo, int K)
{
    const int idx = blockIdx.x * 256 + threadIdx.x;   // 12288 = 128*96
    if (idx >= 12288) return;
    const int col = idx / 96, k = idx - col * 96;
    const float v = (k < K) ? W[(size_t)k * 128 + col] : 0.f;
    const unsigned hb = bf16rtn(v);
    const float r = v - __uint_as_float(hb << 16);
    whi[idx] = (unsigned short)hb;
    wlo[idx] = (unsigned short)bf16rtn(r);
}

// ---------------------------------------------------------------------------
// FUSED GRU via bf16x3 MFMA (round-14 verified). gi never touches HBM.
// ---------------------------------------------------------------------------
__global__ __launch_bounds__(512) void gru_fused_mfma_k(
    const float* __restrict__ cbuf, const unsigned short* __restrict__ whi,
    const unsigned short* __restrict__ wlo, const float* __restrict__ bih,
    const float* __restrict__ bhh, float* __restrict__ h, int M)
{
    __shared__ short lhi[4][4][64][8];   // [rowTile][kChunk][lane][8 bf16]
    __shared__ short llo[4][4][64][8];
    const int t    = threadIdx.x;
    const int lane = t & 63;
    const int w    = t >> 6;
    const int rBase = blockIdx.x * 64;

    const int sRS = t >> 3, sQ = t & 7;
    const int sRow = rBase + sRS;
    const int sRT = sRS >> 4, sLrow = sRS & 15;

    auto stage = [&](const float* __restrict__ A, bool doElu) {
#pragma unroll
        for (int half = 0; half < 2; half++) {
            const int k0 = sQ * 16 + half * 8;
            const int kc = k0 >> 5;
            const int g  = (k0 & 31) >> 3;
            float4 f0 = make_float4(0.f, 0.f, 0.f, 0.f);
            float4 f1 = make_float4(0.f, 0.f, 0.f, 0.f);
            if (sRow < M) {
                f0 = *(const float4*)&A[(size_t)sRow * 128 + k0];
                f1 = *(const float4*)&A[(size_t)sRow * 128 + k0 + 4];
                if (doElu) {
                    f0.x = f0.x > 0.f ? f0.x : expm1f(f0.x);
                    f0.y = f0.y > 0.f ? f0.y : expm1f(f0.y);
                    f0.z = f0.z > 0.f ? f0.z : expm1f(f0.z);
                    f0.w = f0.w > 0.f ? f0.w : expm1f(f0.w);
                    f1.x = f1.x > 0.f ? f1.x : expm1f(f1.x);
                    f1.y = f1.y > 0.f ? f1.y : expm1f(f1.y);
                    f1.z = f1.z > 0.f ? f1.z : expm1f(f1.z);
                    f1.w = f1.w > 0.f ? f1.w : expm1f(f1.w);
                }
            }
            short8v h8, l8;
            split8(f0, f1, h8, l8);
            *(short8v*)&lhi[sRT][kc][sLrow + g * 16][0] = h8;
            *(short8v*)&llo[sRT][kc][sLrow + g * 16][0] = l8;
        }
    };

    f32x4 accr[4], accz[4], accig[4], acchg[4];
#pragma unroll
    for (int rt = 0; rt < 4; rt++) {
        accr[rt]  = (f32x4){0.f, 0.f, 0.f, 0.f};
        accz[rt]  = (f32x4){0.f, 0.f, 0.f, 0.f};
        accig[rt] = (f32x4){0.f, 0.f, 0.f, 0.f};
        acchg[rt] = (f32x4){0.f, 0.f, 0.f, 0.f};
    }

    const int cw   = w * 16 + (lane & 15);   // gate-col [0,128)
    const int koff = (lane >> 4) * 8;

    // ---- pass 1: elu(c) @ Wih.T ----
    stage(cbuf, true);
    __syncthreads();
#pragma unroll
    for (int kc = 0; kc < 4; kc++) {
        short8v bh[3], bl[3];
#pragma unroll
        for (int g = 0; g < 3; g++) {
            const size_t off = (size_t)(g * 128 + cw) * 128 + kc * 32 + koff;
            bh[g] = *(const short8v*)&whi[off];
            bl[g] = *(const short8v*)&wlo[off];
        }
#pragma unroll
        for (int rt = 0; rt < 4; rt++) {
            const short8v ah = *(const short8v*)&lhi[rt][kc][lane][0];
            const short8v al = *(const short8v*)&llo[rt][kc][lane][0];
            accr[rt]  = __builtin_amdgcn_mfma_f32_16x16x32_bf16(ah, bh[0], accr[rt], 0, 0, 0);
            accr[rt]  = __builtin_amdgcn_mfma_f32_16x16x32_bf16(al, bh[0], accr[rt], 0, 0, 0);
            accr[rt]  = __builtin_amdgcn_mfma_f32_16x16x32_bf16(ah, bl[0], accr[rt], 0, 0, 0);
            accz[rt]  = __builtin_amdgcn_mfma_f32_16x16x32_bf16(ah, bh[1], accz[rt], 0, 0, 0);
            accz[rt]  = __builtin_amdgcn_mfma_f32_16x16x32_bf16(al, bh[1], accz[rt], 0, 0, 0);
            accz[rt]  = __builtin_amdgcn_mfma_f32_16x16x32_bf16(ah, bl[1], accz[rt], 0, 0, 0);
            accig[rt] = __builtin_amdgcn_mfma_f32_16x16x32_bf16(ah, bh[2], accig[rt], 0, 0, 0);
            accig[rt] = __builtin_amdgcn_mfma_f32_16x16x32_bf16(al, bh[2], accig[rt], 0, 0, 0);
            accig[rt] = __builtin_amdgcn_mfma_f32_16x16x32_bf16(ah, bl[2], accig[rt], 0, 0, 0);
        }
    }
    __syncthreads();   // all waves done reading LDS before re-stage

    // ---- pass 2: h @ Whh.T (r,z accumulate into same accs) ----
    stage(h, false);
    __syncthreads();
#pragma unroll
    for (int kc = 0; kc < 4; kc++) {
        short8v bh[3], bl[3];
#pragma unroll
        for (int g = 0; g < 3; g++) {
            const size_t off = (size_t)(384 + g * 128 + cw) * 128 + kc * 32 + koff;
            bh[g] = *(const short8v*)&whi[off];
            bl[g] = *(const short8v*)&wlo[off];
        }
#pragma unroll
        for (int rt = 0; rt < 4; rt++) {
            const short8v ah = *(const short8v*)&lhi[rt][kc][lane][0];
            const short8v al = *(const short8v*)&llo[rt][kc][lane][0];
            accr[rt]  = __builtin_amdgcn_mfma_f32_16x16x32_bf16(ah, bh[0], accr[rt], 0, 0, 0);
            accr[rt]  = __builtin_amdgcn_mfma_f32_16x16x32_bf16(al, bh[0], accr[rt], 0, 0, 0);
            accr[rt]  = __builtin_amdgcn_mfma_f32_16x16x32_bf16(ah, bl[0], accr[rt], 0, 0, 0);
            accz[rt]  = __builtin_amdgcn_mfma_f32_16x16x32_bf16(ah, bh[1], accz[rt], 0, 0, 0);
            accz[rt]  = __builtin_amdgcn_mfma_f32_16x16x32_bf16(al, bh[1], accz[rt], 0, 0, 0);
            accz[rt]  = __builtin_amdgcn_mfma_f32_16x16x32_bf16(ah, bl[1], accz[rt], 0, 0, 0);
            acchg[rt] = __builtin_amdgcn_mfma_f32_16x16x32_bf16(ah, bh[2], acchg[rt], 0, 0, 0);
            acchg[rt] = __builtin_amdgcn_mfma_f32_16x16x32_bf16(al, bh[2], acchg[rt], 0, 0, 0);
            acchg[rt] = __builtin_amdgcn_mfma_f32_16x16x32_bf16(ah, bl[2], acchg[rt], 0, 0, 0);
        }
    }

    // ---- gate epilogue ----
    const float br_  = bih[cw] + bhh[cw];
    const float bz_  = bih[128 + cw] + bhh[128 + cw];
    const float big_ = bih[256 + cw];
    const float bhg_ = bhh[256 + cw];
#pragma unroll
    for (int rt = 0; rt < 4; rt++) {
        const int r0 = rBase + rt * 16 + ((lane >> 4) << 2);
#pragma unroll
        for (int i = 0; i < 4; i++) {
            const int row = r0 + i;
            if (row >= M) continue;
            const float hv = h[(size_t)row * 128 + cw];
            const float r  = 1.f / (1.f + expf(-(accr[rt][i] + br_)));
            const float z  = 1.f / (1.f + expf(-(accz[rt][i] + bz_)));
            const float nn = tanhf(accig[rt][i] + big_ + r * (acchg[rt][i] + bhg_));
            h[(size_t)row * 128 + cw] = fmaxf((1.f - z) * nn + z * hv, 0.f);
        }
    }
}

// ---------------------------------------------------------------------------
// Single-output MFMA GEMM (K=128, NC=128), bf16x3 (round-13 verified).
// ---------------------------------------------------------------------------
__global__ __launch_bounds__(512) void mfma128_k(
    const float* __restrict__ A, const unsigned short* __restrict__ whi,
    const unsigned short* __restrict__ wlo, const float* __restrict__ bias,
    float* __restrict__ C, int M, int actOut)
{
    __shared__ short lhi[4][4][64][8];
    __shared__ short llo[4][4][64][8];
    const int t    = threadIdx.x;
    const int lane = t & 63;
    const int w    = t >> 6;
    const int rBase = blockIdx.x * 64;

    {
        const int rS = t >> 3, q = t & 7;
        const int row = rBase + rS;
        const int rt = rS >> 4, lrow = rS & 15;
#pragma unroll
        for (int half = 0; half < 2; half++) {
            const int k0 = q * 16 + half * 8;
            const int kc = k0 >> 5;
            const int g  = (k0 & 31) >> 3;
            float4 f0 = make_float4(0.f, 0.f, 0.f, 0.f);
            float4 f1 = make_float4(0.f, 0.f, 0.f, 0.f);
            if (row < M) {
                f0 = *(const float4*)&A[(size_t)row * 128 + k0];
                f1 = *(const float4*)&A[(size_t)row * 128 + k0 + 4];
            }
            short8v h8, l8;
            split8(f0, f1, h8, l8);
            *(short8v*)&lhi[rt][kc][lrow + g * 16][0] = h8;
            *(short8v*)&llo[rt][kc][lrow + g * 16][0] = l8;
        }
    }
    __syncthreads();

    f32x4 acc[4];
#pragma unroll
    for (int rt = 0; rt < 4; rt++) acc[rt] = (f32x4){0.f, 0.f, 0.f, 0.f};

    const int cw   = w * 16 + (lane & 15);
    const int koff = (lane >> 4) * 8;

#pragma unroll
    for (int kc = 0; kc < 4; kc++) {
        const size_t off = (size_t)cw * 128 + kc * 32 + koff;
        const short8v bh = *(const short8v*)&whi[off];
        const short8v bl = *(const short8v*)&wlo[off];
#pragma unroll
        for (int rt = 0; rt < 4; rt++) {
            const short8v ah = *(const short8v*)&lhi[rt][kc][lane][0];
            const short8v al = *(const short8v*)&llo[rt][kc][lane][0];
            acc[rt] = __builtin_amdgcn_mfma_f32_16x16x32_bf16(ah, bh, acc[rt], 0, 0, 0);
            acc[rt] = __builtin_amdgcn_mfma_f32_16x16x32_bf16(al, bh, acc[rt], 0, 0, 0);
            acc[rt] = __builtin_amdgcn_mfma_f32_16x16x32_bf16(ah, bl, acc[rt], 0, 0, 0);
        }
    }

    const float b0 = bias[cw];
#pragma unroll
    for (int rt = 0; rt < 4; rt++) {
        const int r0 = rBase + rt * 16 + ((lane >> 4) << 2);
#pragma unroll
        for (int i = 0; i < 4; i++) {
            const int row = r0 + i;
            if (row >= M) continue;
            float v = acc[rt][i] + b0;
            if (actOut == ACT_LEAKY)      v = v > 0.f ? v : 0.01f * v;
            else if (actOut == ACT_RELU)  v = fmaxf(v, 0.f);
            C[(size_t)row * 128 + cw] = v;
        }
    }
}

// ---------------------------------------------------------------------------
// Gathered MFMA GEMM, K padded to 96 (for K1=74 [+12 bond] GetContext mats):
//   C[r] = act( concat(A1[idx?idx[r]:r][0:K1], A2?A2[r][0:12]:0, 0-pad) @ W )
// W pre-split by wsplitT96_k ([col][96], zero-padded -> padding exact).
// ---------------------------------------------------------------------------
__global__ __launch_bounds__(512) void mfma96_k(
    const float* __restrict__ A1, const float* __restrict__ A2,
    const int* __restrict__ idx,
    const unsigned short* __restrict__ whi, const unsigned short* __restrict__ wlo,
    const float* __restrict__ bias, float* __restrict__ C,
    int M, int K1, int actOut)
{
    __shared__ short lhi[4][3][64][8];
    __shared__ short llo[4][3][64][8];
    const int t    = threadIdx.x;
    const int lane = t & 63;
    const int w    = t >> 6;
    const int rBase = blockIdx.x * 64;

    {
        const int rS = t >> 3, q = t & 7;
        const int row = rBase + rS;
        const int rt = rS >> 4, lrow = rS & 15;
#pragma unroll
        for (int half = 0; half < 2; half++) {
            const int k0 = q * 16 + half * 8;
            if (k0 >= 96) continue;
            const int kc = k0 >> 5;
            const int g  = (k0 & 31) >> 3;
            float v[8] = {0.f, 0.f, 0.f, 0.f, 0.f, 0.f, 0.f, 0.f};
            if (row < M) {
                const int ar = idx ? idx[row] : row;
                const float* __restrict__ a1 = A1 + (size_t)ar * K1;
#pragma unroll
                for (int j = 0; j < 8; j++) {
                    const int k = k0 + j;
                    if (k < K1)                 v[j] = a1[k];
                    else if (A2 && k < K1 + 12) v[j] = A2[(size_t)row * 12 + (k - K1)];
                }
            }
            short8v h8, l8;
            split8(make_float4(v[0], v[1], v[2], v[3]),
                   make_float4(v[4], v[5], v[6], v[7]), h8, l8);
            *(short8v*)&lhi[rt][kc][lrow + g * 16][0] = h8;
            *(short8v*)&llo[rt][kc][lrow + g * 16][0] = l8;
        }
    }
    __syncthreads();

    f32x4 acc[4];
#pragma unroll
    for (int rt = 0; rt < 4; rt++) acc[rt] = (f32x4){0.f, 0.f, 0.f, 0.f};

    const int cw   = w * 16 + (lane & 15);
    const int koff = (lane >> 4) * 8;

#pragma unroll
    for (int kc = 0; kc < 3; kc++) {
        const size_t off = (size_t)cw * 96 + kc * 32 + koff;
        const short8v bh = *(const short8v*)&whi[off];
        const short8v bl = *(const short8v*)&wlo[off];
#pragma unroll
        for (int rt = 0; rt < 4; rt++) {
            const short8v ah = *(const short8v*)&lhi[rt][kc][lane][0];
            const short8v al = *(const short8v*)&llo[rt][kc][lane][0];
            acc[rt] = __builtin_amdgcn_mfma_f32_16x16x32_bf16(ah, bh, acc[rt], 0, 0, 0);
            acc[rt] = __builtin_amdgcn_mfma_f32_16x16x32_bf16(al, bh, acc[rt], 0, 0, 0);
            acc[rt] = __builtin_amdgcn_mfma_f32_16x16x32_bf16(ah, bl, acc[rt], 0, 0, 0);
        }
    }

    const float b0 = bias[cw];
#pragma unroll
    for (int rt = 0; rt < 4; rt++) {
        const int r0 = rBase + rt * 16 + ((lane >> 4) << 2);
#pragma unroll
        for (int i = 0; i < 4; i++) {
            const int row = r0 + i;
            if (row >= M) continue;
            float v = acc[rt][i] + b0;
            if (actOut == ACT_LEAKY)      v = v > 0.f ? v : 0.01f * v;
            else if (actOut == ACT_RELU)  v = fmaxf(v, 0.f);
            C[(size_t)row * 128 + cw] = v;
        }
    }
}

// ---------------------------------------------------------------------------
// per-node dual dot: pd[i] = h[i]·wa, ps[i] = h[i]·wb   (one wave per node)
// ---------------------------------------------------------------------------
__global__ __launch_bounds__(256) void node_dots_k(
    const float* __restrict__ h, const float* __restrict__ wa,
    const float* __restrict__ wb, float* __restrict__ pd, float* __restrict__ ps, int n)
{
    const int i = blockIdx.x * 4 + (threadIdx.x >> 6);
    const int l = threadIdx.x & 63;
    if (i >= n) return;
    const float2 hv = *(const float2*)&h[(size_t)i * 128 + l * 2];
    float a = hv.x * wa[l * 2] + hv.y * wa[l * 2 + 1];
    float b = 0.f;
    if (wb) b = hv.x * wb[l * 2] + hv.y * wb[l * 2 + 1];
#pragma unroll
    for (int o = 32; o; o >>= 1) {
        a += __shfl_down(a, o, 64);
        b += __shfl_down(b, o, 64);
    }
    if (l == 0) {
        pd[i] = a;
        if (ps) ps[i] = b;
    }
}

// GetContext edge logits from precomputed pe: lg = leaky(pd[dst]+pe[e]+b2); atomicMax m
__global__ __launch_bounds__(256) void edge_lgc_k(
    const float* __restrict__ pd, const float* __restrict__ pe,
    const float* __restrict__ b2, const int* __restrict__ dst,
    float* __restrict__ lg, unsigned* __restrict__ m_u, int E)
{
    const int e = blockIdx.x * blockDim.x + threadIdx.x;
    if (e >= E) return;
    const int d = dst[e];
    const float v = leakyf(pd[d] + pe[e] + b2[0]);
    lg[e] = v;
    atomicMax(&m_u[d], fenc(v));
}

// e = exp(lg - m[dst]); s[dst] += e
__global__ __launch_bounds__(256) void edge_exp_k(
    float* __restrict__ lg, const unsigned* __restrict__ m_u,
    float* __restrict__ s, const int* __restrict__ dst, int E)
{
    const int e = blockIdx.x * blockDim.x + threadIdx.x;
    if (e >= E) return;
    const int d = dst[e];
    const float ex = expf(lg[e] - fdec(m_u[d]));
    lg[e] = ex;
    atomicAdd(&s[d], ex);
}

// c[dst[e]] += (ee[e]/s[dst[e]]) * rows[e]   (64 lanes x 2 cols) -- GetContext only
__global__ __launch_bounds__(256) void scatter_c_k(
    const float* __restrict__ rows,
    const float* __restrict__ ee, const float* __restrict__ s,
    const int* __restrict__ dst, float* __restrict__ c, int E)
{
    const long long gid = (long long)blockIdx.x * blockDim.x + threadIdx.x;
    const int e = (int)(gid >> 6);
    const int l = (int)(gid & 63);
    if (e >= E) return;
    const int d = dst[e];
    const float a = ee[e] / s[d];
    const float2 v = *(const float2*)&rows[(size_t)e * 128 + l * 2];
    atomicAdd(&c[(size_t)d * 128 + l * 2], a * v.x);
    atomicAdd(&c[(size_t)d * 128 + l * 2 + 1], a * v.y);
}

// ---------------------------------------------------------------------------
// CSR build: histogram -> exclusive scan -> fill
// ---------------------------------------------------------------------------
__global__ __launch_bounds__(256) void hist_k(
    const int* __restrict__ dst, unsigned* __restrict__ cnt, int E)
{
    const int e = blockIdx.x * blockDim.x + threadIdx.x;
    if (e < E) atomicAdd(&cnt[dst[e]], 1u);
}

__global__ __launch_bounds__(1024) void scan_k(
    const unsigned* __restrict__ cnt, int* __restrict__ rp, int N)
{
    __shared__ int wsum[16];
    __shared__ int carry;
    const int t = threadIdx.x, lane = t & 63, wid = t >> 6;
    if (t == 0) carry = 0;
    __syncthreads();
    for (int base = 0; base < N; base += 1024) {
        const int i = base + t;
        const int v = (i < N) ? (int)cnt[i] : 0;
        int x = v;
#pragma unroll
        for (int o = 1; o < 64; o <<= 1) {
            const int y = __shfl_up(x, o, 64);
            if (lane >= o) x += y;
        }
        if (lane == 63) wsum[wid] = x;
        __syncthreads();
        if (wid == 0) {
            const int wv = (lane < 16) ? wsum[lane] : 0;
            int wx = wv;
#pragma unroll
            for (int o = 1; o < 16; o <<= 1) {
                const int y = __shfl_up(wx, o, 64);
                if (lane >= o) wx += y;
            }
            if (lane < 16) wsum[lane] = wx - wv;   // exclusive wave offsets
        }
        __syncthreads();
        const int excl = carry + wsum[wid] + x - v;
        if (i < N) rp[i] = excl;
        __syncthreads();
        if (t == 1023) carry = excl + v;
        __syncthreads();
    }
    if (t == 0) rp[N] = carry;
}

__global__ __launch_bounds__(256) void fill_csr_k(
    const int* __restrict__ dst, int* __restrict__ pos,
    int* __restrict__ eidx, int E)
{
    const int e = blockIdx.x * blockDim.x + threadIdx.x;
    if (e < E) {
        const int p = atomicAdd(&pos[dst[e]], 1);
        eidx[p] = e;
    }
}

// ---------------------------------------------------------------------------
// Fused per-node edge softmax + weighted gather (layers)
// ---------------------------------------------------------------------------
__global__ __launch_bounds__(256) void layer_gather_k(
    const int* __restrict__ rp, const int* __restrict__ eidx,
    const int* __restrict__ src,
    const float* __restrict__ pd, const float* __restrict__ ps,
    const float* __restrict__ bpe,
    const float* __restrict__ hp, float* __restrict__ c, int N)
{
    const int d = blockIdx.x * 4 + (threadIdx.x >> 6);
    const int l = threadIdx.x & 63;
    if (d >= N) return;
    const int beg = rp[d], end = rp[d + 1];
    float acc0 = 0.f, acc1 = 0.f;
    if (beg < end) {
        const float pdd = pd[d];
        const float b   = bpe[0];
        float m = -3.4e38f;
        for (int e = beg + l; e < end; e += 64)
            m = fmaxf(m, leakyf(pdd + ps[src[eidx[e]]] + b));
#pragma unroll
        for (int o = 32; o; o >>= 1) m = fmaxf(m, __shfl_xor(m, o, 64));
        float s = 0.f;
        for (int e = beg + l; e < end; e += 64)
            s += expf(leakyf(pdd + ps[src[eidx[e]]] + b) - m);
#pragma unroll
        for (int o = 32; o; o >>= 1) s += __shfl_xor(s, o, 64);
        const float inv = 1.f / s;
        for (int e = beg; e < end; ++e) {
            const int sr = src[eidx[e]];                 // uniform -> broadcast
            const float a = expf(leakyf(pdd + ps[sr] + b) - m) * inv;
            const float2 v = *(const float2*)&hp[(size_t)sr * 128 + l * 2];
            acc0 = fmaf(a, v.x, acc0);
            acc1 = fmaf(a, v.y, acc1);
        }
    }
    *(float2*)&c[(size_t)d * 128 + l * 2] = make_float2(acc0, acc1);
}

// segmented mean readout (node_graph_ids sorted): one wave per graph
__global__ __launch_bounds__(256) void readout_mean_k(
    const float* __restrict__ x, const int* __restrict__ grp,
    float* __restrict__ out, int G)
{
    const int g = blockIdx.x * 4 + (threadIdx.x >> 6);
    const int l = threadIdx.x & 63;
    if (g >= G) return;
    const int beg = grp[g], end = grp[g + 1];
    float s0 = 0.f, s1 = 0.f;
    for (int r = beg; r < end; ++r) {
        const float2 v = *(const float2*)&x[(size_t)r * 128 + l * 2];
        s0 += v.x;
        s1 += v.y;
    }
    const float inv = 1.f / fmaxf((float)(end - beg), 1.f);
    *(float2*)&out[(size_t)g * 128 + l * 2] = make_float2(s0 * inv, s1 * inv);
}

// ---------------------------------------------------------------------------
extern "C" void kernel_launch(void* const* d_in, const int* in_sizes, int n_in,
                              void* d_out, int out_size, void* d_ws, size_t ws_size,
                              hipStream_t stream)
{
    const float* atom   = (const float*)d_in[0];
    const float* bond   = (const float*)d_in[1];
    const int*   src    = (const int*)d_in[2];
    const int*   dst    = (const int*)d_in[3];
    const int*   ngid   = (const int*)d_in[4];
    const float* W_node = (const float*)d_in[5];
    const float* b_node = (const float*)d_in[6];
    const float* W_e1   = (const float*)d_in[7];
    const float* b_e1   = (const float*)d_in[8];
    const float* W_e2   = (const float*)d_in[9];
    const float* b_e2   = (const float*)d_in[10];
    const float* W_et   = (const float*)d_in[11];
    const float* b_et   = (const float*)d_in[12];
    const float* g0_Wih = (const float*)d_in[13];
    const float* g0_bih = (const float*)d_in[14];
    const float* g0_Whh = (const float*)d_in[15];
    const float* g0_bhh = (const float*)d_in[16];
    const float* Wpe    = (const float*)d_in[17];
    const float* bpe    = (const float*)d_in[18];
    const float* Wpn    = (const float*)d_in[19];
    const float* bpn    = (const float*)d_in[20];
    const float* gWih   = (const float*)d_in[21];
    const float* gbih   = (const float*)d_in[22];
    const float* gWhh   = (const float*)d_in[23];
    const float* gbhh   = (const float*)d_in[24];
    const float* Wr1    = (const float*)d_in[25];
    const float* br1    = (const float*)d_in[26];
    const float* Wr2    = (const float*)d_in[27];
    const float* br2    = (const float*)d_in[28];

    const int N = in_sizes[0] / 74;
    const int E = in_sizes[1] / 12;
    const int G = out_size / 128;
    const int L = in_sizes[18];   // bpe is [L][1]

    char* w = (char*)d_ws;
    auto align256 = [](size_t b) { return (b + 255) & ~(size_t)255; };
    auto alloc = [&](size_t bytes) {
        void* p = (void*)w;
        w += align256(bytes);
        return p;
    };
    float*    h    = (float*)alloc((size_t)N * 128 * 4);
    float*    c    = (float*)alloc((size_t)N * 128 * 4);
    float*    hp   = (float*)alloc((size_t)N * 128 * 4);
    int*      rp   = (int*)alloc((size_t)(N + 1) * 4);
    int*      posb = (int*)alloc((size_t)N * 4);
    int*      eidx = (int*)alloc((size_t)E * 4);
    int*      grp  = (int*)alloc((size_t)(G + 1) * 4);
    // weight slots: GRU 12 x 98304, T128 14 x 16384, T96 2 x 12288
    unsigned short* gwHi  = (unsigned short*)alloc((size_t)12 * 98304 * 2);
    unsigned short* gwLo  = (unsigned short*)alloc((size_t)12 * 98304 * 2);
    unsigned short* wtHi  = (unsigned short*)alloc((size_t)14 * 16384 * 2);
    unsigned short* wtLo  = (unsigned short*)alloc((size_t)14 * 16384 * 2);
    unsigned short* w96Hi = (unsigned short*)alloc((size_t)2 * 12288 * 2);
    unsigned short* w96Lo = (unsigned short*)alloc((size_t)2 * 12288 * 2);
    float*    pd   = (float*)alloc((size_t)N * 4);
    float*    ps   = (float*)alloc((size_t)N * 4);
    unsigned* m_u  = (unsigned*)alloc((size_t)N * 4);
    float*    sden = (float*)alloc((size_t)N * 4);
    float*    pe   = (float*)alloc((size_t)E * 4);
    float*    lg   = (float*)alloc((size_t)E * 4);
    if ((size_t)(w - (char*)d_ws) > ws_size) {
        fprintf(stderr, "kernel_launch: ws too small: need %zu, have %zu\n",
                (size_t)(w - (char*)d_ws), ws_size);
        return;
    }
    float* out = (float*)d_out;

    const dim3 blk(256);
    auto g64 = [](int M) { return dim3((unsigned)((M + 63) / 64)); };
    const dim3 gEdge((unsigned)((E + 255) / 256));
    const dim3 gWave4N((unsigned)((N + 3) / 4));
    const int  Ecap = N;           // hp holds up to N rows

    // ---------------- pre-split ALL weights up front ----------------
    wsplit_k<<<dim3(96), blk, 0, stream>>>(g0_Wih, g0_Whh, gwHi, gwLo);
    for (int l = 0; l < L; ++l)
        wsplit_k<<<dim3(96), blk, 0, stream>>>(
            gWih + (size_t)l * 49152, gWhh + (size_t)l * 49152,
            gwHi + (size_t)(l + 1) * 98304, gwLo + (size_t)(l + 1) * 98304);
    for (int l = 0; l < L; ++l)
        wsplitT_k<<<dim3(64), blk, 0, stream>>>(
            Wpn + (size_t)l * 16384, wtHi + (size_t)l * 16384, wtLo + (size_t)l * 16384);
    wsplitT_k<<<dim3(64), blk, 0, stream>>>(W_et, wtHi + (size_t)11 * 16384, wtLo + (size_t)11 * 16384);
    wsplitT_k<<<dim3(64), blk, 0, stream>>>(Wr1,  wtHi + (size_t)12 * 16384, wtLo + (size_t)12 * 16384);
    wsplitT_k<<<dim3(64), blk, 0, stream>>>(Wr2,  wtHi + (size_t)13 * 16384, wtLo + (size_t)13 * 16384);
    wsplitT96_k<<<dim3(48), blk, 0, stream>>>(W_e1,   w96Hi,         w96Lo,         86);
    wsplitT96_k<<<dim3(48), blk, 0, stream>>>(W_node, w96Hi + 12288, w96Lo + 12288, 74);

    auto run_gru = [&](int slot, const float* bih, const float* bhh) {
        gru_fused_mfma_k<<<g64(N), dim3(512), 0, stream>>>(
            c, gwHi + (size_t)slot * 98304, gwLo + (size_t)slot * 98304, bih, bhh, h, N);
    };
    auto run_mfma128 = [&](const float* A, int slot, const float* bias,
                           float* C, int act) {
        mfma128_k<<<g64(N), dim3(512), 0, stream>>>(
            A, wtHi + (size_t)slot * 16384, wtLo + (size_t)slot * 16384, bias, C, N, act);
    };

    // ---------------- CSR build (graph static across layers) ----------------
    hipMemsetAsync(m_u, 0, (size_t)N * 4, stream);
    hist_k<<<gEdge, blk, 0, stream>>>(dst, m_u, E);
    scan_k<<<dim3(1), dim3(1024), 0, stream>>>(m_u, rp, N);
    hipMemcpyAsync(posb, rp, (size_t)N * 4, hipMemcpyDeviceToDevice, stream);
    fill_csr_k<<<gEdge, blk, 0, stream>>>(dst, posb, eidx, E);
    // graph rowptr from sorted ngid
    hipMemsetAsync(m_u, 0, (size_t)G * 4, stream);
    hist_k<<<dim3((unsigned)((N + 255) / 256)), blk, 0, stream>>>(ngid, m_u, N);
    scan_k<<<dim3(1), dim3(1024), 0, stream>>>(m_u, grp, G);

    // ---------------- GetContext ----------------
    mfma96_k<<<g64(N), dim3(512), 0, stream>>>(
        atom, nullptr, nullptr, w96Hi + 12288, w96Lo + 12288, b_node, h, N, 74, ACT_LEAKY);
    node_dots_k<<<gWave4N, blk, 0, stream>>>(h, W_e2, nullptr, pd, nullptr, N);
    // pass A: pe[e] = he1[e] . W_e2[128:256]  (chunked, he1 in hp, discarded)
    for (int base = 0; base < E; base += Ecap) {
        const int ec = (E - base) < Ecap ? (E - base) : Ecap;
        mfma96_k<<<g64(ec), dim3(512), 0, stream>>>(
            atom, bond + (size_t)base * 12, src + base, w96Hi, w96Lo, b_e1,
            hp, ec, 74, ACT_LEAKY);
        node_dots_k<<<dim3((unsigned)((ec + 3) / 4)), blk, 0, stream>>>(
            hp, W_e2 + 128, nullptr, pe + base, nullptr, ec);
    }
    hipMemsetAsync(m_u, 0, (size_t)N * 4, stream);
    hipMemsetAsync(sden, 0, (size_t)N * 4, stream);
    edge_lgc_k<<<gEdge, blk, 0, stream>>>(pd, pe, b_e2, dst, lg, m_u, E);
    edge_exp_k<<<gEdge, blk, 0, stream>>>(lg, m_u, sden, dst, E);
    // pass B: recompute he1 chunk, scatter a*he1 into c; then c = c@W_et + b_et
    hipMemsetAsync(c, 0, (size_t)N * 128 * 4, stream);
    for (int base = 0; base < E; base += Ecap) {
        const int ec = (E - base) < Ecap ? (E - base) : Ecap;
        mfma96_k<<<g64(ec), dim3(512), 0, stream>>>(
            atom, bond + (size_t)base * 12, src + base, w96Hi, w96Lo, b_e1,
            hp, ec, 74, ACT_LEAKY);
        scatter_c_k<<<dim3((unsigned)(((long long)ec * 64 + 255) / 256)), blk, 0, stream>>>(
            hp, lg + base, sden, dst + base, c, ec);
    }
    run_mfma128(c, 11, b_et, c, ACT_NONE);
    run_gru(0, g0_bih, g0_bhh);

    // ---------------- 11 GNN layers ----------------
    for (int l = 0; l < L; ++l) {
        node_dots_k<<<gWave4N, blk, 0, stream>>>(
            h, Wpe + (size_t)l * 256, Wpe + (size_t)l * 256 + 128, pd, ps, N);
        run_mfma128(h, l, bpn + (size_t)l * 128, hp, ACT_NONE);
        layer_gather_k<<<gWave4N, blk, 0, stream>>>(
            rp, eidx, src, pd, ps, bpe + l, hp, c, N);
        run_gru(l + 1, gbih + (size_t)l * 384, gbhh + (size_t)l * 384);
    }

    // ---------------- readout ----------------
    run_mfma128(h, 12, br1, c, ACT_RELU);
    run_mfma128(c, 13, br2, hp, ACT_NONE);
    readout_mean_k<<<dim3((unsigned)((G + 3) / 4)), blk, 0, stream>>>(hp, grp, out, G);

    (void)n_in;
}